// Round 2
// baseline (920.849 us; speedup 1.0000x reference)
//
#include <hip/hip_runtime.h>
#include <hip/hip_bf16.h>

typedef __hip_bfloat16 bf16;

#define B_   2
#define L_   1024
#define DM_  512
#define DI_  1024
#define N_   16
#define K_   12
#define DTR_ 32

static constexpr int BLD  = B_ * L_ * DI_;   // 2097152
static constexpr int BL   = B_ * L_;         // 2048

__device__ __forceinline__ float toF(float x) { return x; }
__device__ __forceinline__ float toF(bf16 x)  { return __bfloat162float(x); }

__device__ __forceinline__ float siluf(float x) { return x / (1.f + __expf(-x)); }
__device__ __forceinline__ float softplusf(float x) {
    return fmaxf(x, 0.f) + log1pf(expf(-fabsf(x)));
}
__device__ __forceinline__ float seluf(float x) {
    const float lam = 1.0507009873554805f, alp = 1.6732632423543772f;
    return x > 0.f ? lam * x : lam * alp * (expf(x) - 1.f);
}

// ---------------- LayerNorm: one wave per row of 512 ----------------
__global__ __launch_bounds__(256) void ln_kernel(
    const float* __restrict__ x, const float* __restrict__ w, const float* __restrict__ b,
    const float* __restrict__ mask, float* __restrict__ y)
{
    int row  = blockIdx.x * 4 + (threadIdx.x >> 6);
    int lane = threadIdx.x & 63;
    const float* xr = x + (size_t)row * DM_;
    float mval = mask ? mask[row] : 1.0f;
    float v[8];
    float s = 0.f, ss = 0.f;
#pragma unroll
    for (int i = 0; i < 8; i++) {
        v[i] = xr[lane + i * 64] * mval;
        s += v[i]; ss += v[i] * v[i];
    }
#pragma unroll
    for (int o = 32; o >= 1; o >>= 1) { s += __shfl_xor(s, o); ss += __shfl_xor(ss, o); }
    float mean = s * (1.f / DM_);
    float var  = ss * (1.f / DM_) - mean * mean;
    float r    = rsqrtf(var + 1e-5f);
    float* yr = y + (size_t)row * DM_;
#pragma unroll
    for (int i = 0; i < 8; i++) {
        int c = lane + i * 64;
        yr[c] = (v[i] - mean) * r * w[c] + b[c];
    }
}

// ---------------- GEMM: C(M,N) = A(M,K) @ W(N,K)^T, fp32 accumulate ----------------
// MODE 0: plain   1: bias+softplus   2: bias+selu   3: bias+residual
template<int MODE>
__global__ __launch_bounds__(256) void gemm_k(
    const float* __restrict__ A, int lda,
    const float* __restrict__ W,
    float* __restrict__ C,
    const float* __restrict__ bias,
    const float* __restrict__ resid,
    int M, int N, int Kd)
{
    __shared__ float As[16][68];
    __shared__ float Ws[16][68];
    int bm = blockIdx.y * 64, bn = blockIdx.x * 64;
    int tid = threadIdx.x;
    int tm = tid & 15, tn = tid >> 4;
    float acc[4][4] = {};
    for (int k0 = 0; k0 < Kd; k0 += 16) {
#pragma unroll
        for (int i = 0; i < 4; i++) {
            int idx = tid + i * 256;
            int m = idx >> 4, kk = idx & 15;
            As[kk][m] = A[(size_t)(bm + m) * lda + k0 + kk];
        }
#pragma unroll
        for (int i = 0; i < 4; i++) {
            int idx = tid + i * 256;
            int n = idx >> 4, kk = idx & 15;
            Ws[kk][n] = W[(size_t)(bn + n) * Kd + k0 + kk];
        }
        __syncthreads();
#pragma unroll
        for (int kk = 0; kk < 16; kk++) {
            float a4[4], w4[4];
#pragma unroll
            for (int i = 0; i < 4; i++) a4[i] = As[kk][tm * 4 + i];
#pragma unroll
            for (int j = 0; j < 4; j++) w4[j] = Ws[kk][tn * 4 + j];
#pragma unroll
            for (int i = 0; i < 4; i++)
#pragma unroll
                for (int j = 0; j < 4; j++)
                    acc[i][j] = fmaf(a4[i], w4[j], acc[i][j]);
        }
        __syncthreads();
    }
#pragma unroll
    for (int i = 0; i < 4; i++) {
        int m = bm + tm * 4 + i;
#pragma unroll
        for (int j = 0; j < 4; j++) {
            int n = bn + tn * 4 + j;
            float v = acc[i][j];
            if (MODE == 1) v = softplusf(v + bias[n]);
            if (MODE == 2) v = seluf(v + bias[n]);
            if (MODE == 3) v = v + bias[n] + resid[(size_t)m * N + n];
            C[(size_t)m * N + n] = v;
        }
    }
}

// ---------------- depthwise causal conv (dir 0) / anti-causal (dir 1) + SiLU ----------------
__global__ __launch_bounds__(256) void conv_silu_kernel(
    const float* __restrict__ xz, const float* __restrict__ cw,
    const float* __restrict__ cb, float* __restrict__ xc)
{
    int dir = blockIdx.y;
    int idx = blockIdx.x * 256 + threadIdx.x;   // over B*L*DI
    int d = idx & (DI_ - 1);
    int l = (idx >> 10) & (L_ - 1);
    int b = idx >> 20;
    float acc = cb[d];
#pragma unroll
    for (int k = 0; k < K_; k++) {
        int ls = (dir == 0) ? (l - (K_ - 1) + k) : (l + (K_ - 1) - k);
        if (ls >= 0 && ls < L_)
            acc = fmaf(cw[d * K_ + k], xz[((size_t)(b * L_ + ls)) * (2 * DI_) + d], acc);
    }
    xc[(size_t)dir * BLD + idx] = siluf(acc);
}

// ---------------- fused selective scan: thread per (b,d,n), serial over L ----------------
__global__ __launch_bounds__(256) void scan_kernel(
    const float* __restrict__ dt,    // [2][B*L*DI]
    const float* __restrict__ xc,    // [2][B*L*DI]
    const float* __restrict__ dbl,   // [2][B*L*64]
    const float* __restrict__ A_log, const float* __restrict__ Dp,
    float* __restrict__ yscan)       // [2][B*L*DI]
{
    int dir = blockIdx.y;
    int b  = blockIdx.x >> 6;        // DI/16 = 64 d-groups
    int dg = blockIdx.x & 63;
    int tid = threadIdx.x;
    int n = tid & 15, dl = tid >> 4;
    int d = dg * 16 + dl;
    size_t base = (size_t)dir * BLD + (size_t)b * L_ * DI_ + d;
    const float* dtp = dt + base;
    const float* xcp = xc + base;
    const float* dblp = dbl + (size_t)dir * (BL * 64) + (size_t)b * L_ * 64;
    float Aval = -expf(A_log[d * N_ + n]);
    float Dd = Dp[d];
    float h = 0.f;
    float* yp = yscan + base;
    for (int i = 0; i < L_; i++) {
        int l = (dir == 0) ? i : (L_ - 1 - i);
        float dtv = dtp[(size_t)l * DI_];
        float xcv = xcp[(size_t)l * DI_];
        float Bv = dblp[l * 64 + DTR_ + n];
        float Cv = dblp[l * 64 + DTR_ + N_ + n];
        float a = __expf(dtv * Aval);
        h = fmaf(a, h, dtv * Bv * xcv);
        float p = h * Cv;
#pragma unroll
        for (int o = 1; o < 16; o <<= 1) p += __shfl_xor(p, o);
        if (n == 0) yp[(size_t)l * DI_] = fmaf(xcv, Dd, p);
    }
}

// ---------------- combine: (y_f + y_b) * silu(z) ----------------
__global__ __launch_bounds__(256) void combine_kernel(
    const float* __restrict__ yscan, const float* __restrict__ xz,
    float* __restrict__ ycomb)
{
    int idx = blockIdx.x * 256 + threadIdx.x;  // over B*L*DI
    int d = idx & (DI_ - 1);
    int bl = idx >> 10;
    float z = xz[(size_t)bl * (2 * DI_) + DI_ + d];
    ycomb[idx] = (yscan[idx] + yscan[idx + BLD]) * siluf(z);
}

extern "C" void kernel_launch(void* const* d_in, const int* in_sizes, int n_in,
                              void* d_out, int out_size, void* d_ws, size_t ws_size,
                              hipStream_t stream) {
    const float* x     = (const float*)d_in[0];
    const float* mask  = (const float*)d_in[1];
    const float* n1w   = (const float*)d_in[2];
    const float* n1b   = (const float*)d_in[3];
    const float* n2w   = (const float*)d_in[4];
    const float* n2b   = (const float*)d_in[5];
    const float* ff1w  = (const float*)d_in[6];
    const float* ff1b  = (const float*)d_in[7];
    const float* ff2w  = (const float*)d_in[8];
    const float* ff2b  = (const float*)d_in[9];
    const float* inpw  = (const float*)d_in[10];
    const float* convw = (const float*)d_in[11];
    const float* convb = (const float*)d_in[12];
    const float* xpw   = (const float*)d_in[13];
    const float* dtpw  = (const float*)d_in[14];
    const float *A_log, *Dp, *outpw, *dtpb;
    if (in_sizes[15] == DI_ * N_) {          // dict order: A_log, D, out_proj_w, dt_proj_b
        A_log = (const float*)d_in[15]; Dp = (const float*)d_in[16];
        outpw = (const float*)d_in[17]; dtpb = (const float*)d_in[18];
    } else {                                  // signature order: dt_proj_b, A_log, D, out_proj_w
        dtpb = (const float*)d_in[15]; A_log = (const float*)d_in[16];
        Dp = (const float*)d_in[17]; outpw = (const float*)d_in[18];
    }

    float* ws = (float*)d_ws;
    float* xz     = ws;                       // 4M floats (reused as hbuf for ff1 output)
    float* xn     = ws + 4194304;             // 1M (reused as mo_n)
    float* xc     = ws + 5242880;             // 4M  [2][B*L*DI]
    float* dblb   = ws + 9437184;             // 256K [2][B*L*64]
    float* dtb    = ws + 9699328;             // 4M  [2][B*L*DI]
    float* yscan  = ws + 13893632;            // 4M  [2][B*L*DI]
    float* ycomb  = ws + 18087936;            // 2M
    float* moraw  = ws + 20185088;            // 1M

    // 1. xn = LN(x)
    ln_kernel<<<dim3(BL / 4), 256, 0, stream>>>(x, n1w, n1b, nullptr, xn);
    // 2. xz = xn @ in_proj_w^T   (2048 x 2048)
    gemm_k<0><<<dim3(2048 / 64, BL / 64), 256, 0, stream>>>(
        xn, DM_, inpw, xz, nullptr, nullptr, BL, 2 * DI_, DM_);
    // 3. conv + silu (both dirs)
    conv_silu_kernel<<<dim3(BLD / 256, 2), 256, 0, stream>>>(xz, convw, convb, xc);
    // 4. dbl = xc @ x_proj_w^T per dir (2048 x 64)
    for (int dir = 0; dir < 2; dir++)
        gemm_k<0><<<dim3(1, BL / 64), 256, 0, stream>>>(
            xc + (size_t)dir * BLD, DI_, xpw, dblb + (size_t)dir * BL * 64,
            nullptr, nullptr, BL, 64, DI_);
    // 5. dt = softplus(dt_r @ dt_proj_w^T + b) per dir (2048 x 1024)
    for (int dir = 0; dir < 2; dir++)
        gemm_k<1><<<dim3(DI_ / 64, BL / 64), 256, 0, stream>>>(
            dblb + (size_t)dir * BL * 64, 64, dtpw, dtb + (size_t)dir * BLD,
            dtpb, nullptr, BL, DI_, DTR_);
    // 6. selective scan (both dirs)
    scan_kernel<<<dim3(B_ * 64, 2), 256, 0, stream>>>(dtb, xc, dblb, A_log, Dp, yscan);
    // 7. ycomb = (y_f + y_b) * silu(z)
    combine_kernel<<<dim3(BLD / 256), 256, 0, stream>>>(yscan, xz, ycomb);
    // 8. mo_raw = ycomb @ out_proj_w^T (2048 x 512)
    gemm_k<0><<<dim3(DM_ / 64, BL / 64), 256, 0, stream>>>(
        ycomb, DI_, outpw, moraw, nullptr, nullptr, BL, DM_, DI_);
    // 9. mo_n = LN(mo_raw * mask)
    ln_kernel<<<dim3(BL / 4), 256, 0, stream>>>(moraw, n2w, n2b, mask, xn);
    // 10. h = selu(mo_n @ ff1_w^T + b)  (2048 x 2048), reuse xz as hbuf
    gemm_k<2><<<dim3(2048 / 64, BL / 64), 256, 0, stream>>>(
        xn, DM_, ff1w, xz, ff1b, nullptr, BL, 4 * DM_, DM_);
    // 11. out = h @ ff2_w^T + b + x  -> f32 d_out
    gemm_k<3><<<dim3(DM_ / 64, BL / 64), 256, 0, stream>>>(
        xz, 4 * DM_, ff2w, (float*)d_out, ff2b, x, BL, DM_, 4 * DM_);
}

// Round 3
// 561.228 us; speedup vs baseline: 1.6408x; 1.6408x over previous
//
#include <hip/hip_runtime.h>
#include <hip/hip_bf16.h>

typedef __hip_bfloat16 bf16;

#define B_   2
#define L_   1024
#define DM_  512
#define DI_  1024
#define N_   16
#define K_   12
#define DTR_ 32

static constexpr int BLD  = B_ * L_ * DI_;   // 2097152
static constexpr int BL   = B_ * L_;         // 2048

__device__ __forceinline__ float siluf(float x) { return x / (1.f + __expf(-x)); }
__device__ __forceinline__ float softplusf(float x) {
    return fmaxf(x, 0.f) + log1pf(expf(-fabsf(x)));
}
__device__ __forceinline__ float seluf(float x) {
    const float lam = 1.0507009873554805f, alp = 1.6732632423543772f;
    return x > 0.f ? lam * x : lam * alp * (expf(x) - 1.f);
}

// ---------------- LayerNorm: one wave per row of 512 ----------------
__global__ __launch_bounds__(256) void ln_kernel(
    const float* __restrict__ x, const float* __restrict__ w, const float* __restrict__ b,
    const float* __restrict__ mask, float* __restrict__ y)
{
    int row  = blockIdx.x * 4 + (threadIdx.x >> 6);
    int lane = threadIdx.x & 63;
    const float* xr = x + (size_t)row * DM_;
    float mval = mask ? mask[row] : 1.0f;
    float v[8];
    float s = 0.f, ss = 0.f;
#pragma unroll
    for (int i = 0; i < 8; i++) {
        v[i] = xr[lane + i * 64] * mval;
        s += v[i]; ss += v[i] * v[i];
    }
#pragma unroll
    for (int o = 32; o >= 1; o >>= 1) { s += __shfl_xor(s, o); ss += __shfl_xor(ss, o); }
    float mean = s * (1.f / DM_);
    float var  = ss * (1.f / DM_) - mean * mean;
    float r    = rsqrtf(var + 1e-5f);
    float* yr = y + (size_t)row * DM_;
#pragma unroll
    for (int i = 0; i < 8; i++) {
        int c = lane + i * 64;
        yr[c] = (v[i] - mean) * r * w[c] + b[c];
    }
}

// ---------------- GEMM: C(M,N) = A(M,K) @ W(N,K)^T, fp32 accumulate ----------------
// MODE 0: plain   1: bias[n]+softplus   2: bias[n]+selu   3: bias[n]+residual
// MODE 4: bias[m]+softplus (for transposed-output dt GEMM)
template<int MODE>
__global__ __launch_bounds__(256) void gemm_k(
    const float* __restrict__ A, int lda,
    const float* __restrict__ W, int ldw,
    float* __restrict__ C,
    const float* __restrict__ bias,
    const float* __restrict__ resid,
    int M, int N, int Kd)
{
    __shared__ float As[16][68];
    __shared__ float Ws[16][68];
    int bm = blockIdx.y * 64, bn = blockIdx.x * 64;
    int tid = threadIdx.x;
    int tm = tid & 15, tn = tid >> 4;
    float acc[4][4] = {};
    for (int k0 = 0; k0 < Kd; k0 += 16) {
#pragma unroll
        for (int i = 0; i < 4; i++) {
            int idx = tid + i * 256;
            int m = idx >> 4, kk = idx & 15;
            As[kk][m] = A[(size_t)(bm + m) * lda + k0 + kk];
        }
#pragma unroll
        for (int i = 0; i < 4; i++) {
            int idx = tid + i * 256;
            int n = idx >> 4, kk = idx & 15;
            Ws[kk][n] = W[(size_t)(bn + n) * ldw + k0 + kk];
        }
        __syncthreads();
#pragma unroll
        for (int kk = 0; kk < 16; kk++) {
            float a4[4], w4[4];
#pragma unroll
            for (int i = 0; i < 4; i++) a4[i] = As[kk][tm * 4 + i];
#pragma unroll
            for (int j = 0; j < 4; j++) w4[j] = Ws[kk][tn * 4 + j];
#pragma unroll
            for (int i = 0; i < 4; i++)
#pragma unroll
                for (int j = 0; j < 4; j++)
                    acc[i][j] = fmaf(a4[i], w4[j], acc[i][j]);
        }
        __syncthreads();
    }
#pragma unroll
    for (int i = 0; i < 4; i++) {
        int m = bm + tm * 4 + i;
#pragma unroll
        for (int j = 0; j < 4; j++) {
            int n = bn + tn * 4 + j;
            float v = acc[i][j];
            if (MODE == 1) v = softplusf(v + bias[n]);
            if (MODE == 2) v = seluf(v + bias[n]);
            if (MODE == 3) v = v + bias[n] + resid[(size_t)m * N + n];
            if (MODE == 4) v = softplusf(v + bias[m]);
            C[(size_t)m * N + n] = v;
        }
    }
}

// ---------------- depthwise causal conv (dir 0) / anti-causal (dir 1) + SiLU ----------------
__global__ __launch_bounds__(256) void conv_silu_kernel(
    const float* __restrict__ xz, const float* __restrict__ cw,
    const float* __restrict__ cb, float* __restrict__ xc)
{
    int dir = blockIdx.y;
    int idx = blockIdx.x * 256 + threadIdx.x;   // over B*L*DI
    int d = idx & (DI_ - 1);
    int l = (idx >> 10) & (L_ - 1);
    int b = idx >> 20;
    float acc = cb[d];
#pragma unroll
    for (int k = 0; k < K_; k++) {
        int ls = (dir == 0) ? (l - (K_ - 1) + k) : (l + (K_ - 1) - k);
        if (ls >= 0 && ls < L_)
            acc = fmaf(cw[d * K_ + k], xz[((size_t)(b * L_ + ls)) * (2 * DI_) + d], acc);
    }
    xc[(size_t)dir * BLD + idx] = siluf(acc);
}

// ---------------- transpose [2][BL][DI] -> [2][DI][BL] ----------------
__global__ __launch_bounds__(256) void transpose_kernel(
    const float* __restrict__ in, float* __restrict__ out)
{
    __shared__ float tile[32][33];
    int dir = blockIdx.z;
    int d0 = blockIdx.x * 32, l0 = blockIdx.y * 32;
    const float* ip = in + (size_t)dir * BLD;
    float* op = out + (size_t)dir * BLD;
    int tx = threadIdx.x & 31, ty = threadIdx.x >> 5;   // ty in 0..7
#pragma unroll
    for (int r = 0; r < 4; r++) {
        int l = l0 + ty * 4 + r;
        tile[ty * 4 + r][tx] = ip[(size_t)l * DI_ + d0 + tx];
    }
    __syncthreads();
#pragma unroll
    for (int r = 0; r < 4; r++) {
        int d = d0 + ty * 4 + r;
        op[(size_t)d * BL + l0 + tx] = tile[tx][ty * 4 + r];
    }
}

// ---------------- chunked selective scan ----------------
// block = 256 thr = 16 chunks x 16 n ; one block per (dir, b, d)
__global__ __launch_bounds__(256) void scan_kernel(
    const float* __restrict__ dtT,   // [2][DI][BL]
    const float* __restrict__ xcT,   // [2][DI][BL]
    const float* __restrict__ dbl,   // [2][BL][64]
    const float* __restrict__ A_log, const float* __restrict__ Dp,
    float* __restrict__ yT)          // [2][DI][BL]
{
    __shared__ float sA[16][16];
    __shared__ float sB[16][16];
    __shared__ float sY[1024];
    int d = blockIdx.x, b = blockIdx.y, dir = blockIdx.z;
    int tid = threadIdx.x, n = tid & 15, c = tid >> 4;
    size_t row = ((size_t)dir * DI_ + d) * BL + (size_t)b * L_;
    const float* dtp = dtT + row;
    const float* xcp = xcT + row;
    const float* dblp = dbl + ((size_t)dir * BL + (size_t)b * L_) * 64;
    float Aval = -__expf(A_log[d * N_ + n]);
    float Dd = Dp[d];
    int l0 = c * 64;
    // pass 1: local scan -> chunk summary
    float acum = 1.f, h = 0.f;
    for (int j = 0; j < 64; j += 4) {
        float4 dt4 = *(const float4*)(dtp + l0 + j);
        float4 xc4 = *(const float4*)(xcp + l0 + j);
#pragma unroll
        for (int q = 0; q < 4; q++) {
            float dtv = ((const float*)&dt4)[q];
            float xcv = ((const float*)&xc4)[q];
            float Bv = dblp[(l0 + j + q) * 64 + DTR_ + n];
            float a = __expf(dtv * Aval);
            acum *= a;
            h = fmaf(a, h, dtv * Bv * xcv);
        }
    }
    sA[c][n] = acum;
    sB[c][n] = h;
    __syncthreads();
    // exclusive cross-chunk prefix (<=15 fmas)
    float hp = 0.f;
    for (int cc = 0; cc < c; cc++) hp = fmaf(sA[cc][n], hp, sB[cc][n]);
    // pass 2: rescan with prefix, reduce over n, emit y
    h = hp;
    for (int j = 0; j < 64; j += 4) {
        float4 dt4 = *(const float4*)(dtp + l0 + j);
        float4 xc4 = *(const float4*)(xcp + l0 + j);
#pragma unroll
        for (int q = 0; q < 4; q++) {
            int l = l0 + j + q;
            float dtv = ((const float*)&dt4)[q];
            float xcv = ((const float*)&xc4)[q];
            float Bv = dblp[l * 64 + DTR_ + n];
            float Cv = dblp[l * 64 + DTR_ + N_ + n];
            float a = __expf(dtv * Aval);
            h = fmaf(a, h, dtv * Bv * xcv);
            float p = h * Cv;
            p += __shfl_xor(p, 1); p += __shfl_xor(p, 2);
            p += __shfl_xor(p, 4); p += __shfl_xor(p, 8);
            if (n == 0) sY[l] = fmaf(xcv, Dd, p);
        }
    }
    __syncthreads();
    float* yp = yT + row;
#pragma unroll
    for (int i = 0; i < 4; i++) yp[tid + i * 256] = sY[tid + i * 256];
}

// ---------------- combine + transpose: ycomb[bl][d] = (yT0+yT1)[d][bl] * silu(z) ----------------
__global__ __launch_bounds__(256) void combine_kernel(
    const float* __restrict__ yT, const float* __restrict__ xz,
    float* __restrict__ yc)
{
    __shared__ float tile[32][33];
    int d0 = blockIdx.x * 32, bl0 = blockIdx.y * 32;
    int tx = threadIdx.x & 31, ty = threadIdx.x >> 5;
#pragma unroll
    for (int r = 0; r < 4; r++) {
        int d = d0 + ty * 4 + r;
        tile[ty * 4 + r][tx] = yT[(size_t)d * BL + bl0 + tx]
                             + yT[(size_t)(DI_ + d) * BL + bl0 + tx];
    }
    __syncthreads();
#pragma unroll
    for (int r = 0; r < 4; r++) {
        int bl = bl0 + ty * 4 + r;
        float z = xz[(size_t)bl * (2 * DI_) + DI_ + d0 + tx];
        yc[(size_t)bl * DI_ + d0 + tx] = tile[tx][ty * 4 + r] * siluf(z);
    }
}

extern "C" void kernel_launch(void* const* d_in, const int* in_sizes, int n_in,
                              void* d_out, int out_size, void* d_ws, size_t ws_size,
                              hipStream_t stream) {
    const float* x     = (const float*)d_in[0];
    const float* mask  = (const float*)d_in[1];
    const float* n1w   = (const float*)d_in[2];
    const float* n1b   = (const float*)d_in[3];
    const float* n2w   = (const float*)d_in[4];
    const float* n2b   = (const float*)d_in[5];
    const float* ff1w  = (const float*)d_in[6];
    const float* ff1b  = (const float*)d_in[7];
    const float* ff2w  = (const float*)d_in[8];
    const float* ff2b  = (const float*)d_in[9];
    const float* inpw  = (const float*)d_in[10];
    const float* convw = (const float*)d_in[11];
    const float* convb = (const float*)d_in[12];
    const float* xpw   = (const float*)d_in[13];
    const float* dtpw  = (const float*)d_in[14];
    const float *A_log, *Dp, *outpw, *dtpb;
    if (in_sizes[15] == DI_ * N_) {
        A_log = (const float*)d_in[15]; Dp = (const float*)d_in[16];
        outpw = (const float*)d_in[17]; dtpb = (const float*)d_in[18];
    } else {
        dtpb = (const float*)d_in[15]; A_log = (const float*)d_in[16];
        Dp = (const float*)d_in[17]; outpw = (const float*)d_in[18];
    }

    float* ws = (float*)d_ws;
    float* xz     = ws;                       // 4M  [BL][2DI]   (reused as h for ff1)
    float* xn     = ws + 4194304;             // 1M
    float* xc     = ws + 5242880;             // 4M  [2][BL][DI] (reused as yT after dbl GEMM)
    float* xcT    = ws + 9437184;             // 4M  [2][DI][BL]
    float* dblb   = ws + 13631488;            // 256K [2][BL][64]
    float* dtT    = ws + 13893632;            // 4M  [2][DI][BL]
    float* ycomb  = ws + 18087936;            // 2M
    float* moraw  = ws + 20185088;            // 1M
    float* yT     = xc;                       // alias: xc dead after dbl GEMM

    // 1. xn = LN(x)
    ln_kernel<<<dim3(BL / 4), 256, 0, stream>>>(x, n1w, n1b, nullptr, xn);
    // 2. xz = xn @ in_proj_w^T   (2048 x 2048)
    gemm_k<0><<<dim3(2048 / 64, BL / 64), 256, 0, stream>>>(
        xn, DM_, inpw, DM_, xz, nullptr, nullptr, BL, 2 * DI_, DM_);
    // 3. conv + silu (both dirs)
    conv_silu_kernel<<<dim3(BLD / 256, 2), 256, 0, stream>>>(xz, convw, convb, xc);
    // 4. xcT = transpose(xc)
    transpose_kernel<<<dim3(DI_ / 32, BL / 32, 2), 256, 0, stream>>>(xc, xcT);
    // 5. dbl = xc @ x_proj_w^T per dir (2048 x 64)
    for (int dir = 0; dir < 2; dir++)
        gemm_k<0><<<dim3(1, BL / 64), 256, 0, stream>>>(
            xc + (size_t)dir * BLD, DI_, xpw, DI_, dblb + (size_t)dir * BL * 64,
            nullptr, nullptr, BL, 64, DI_);
    // 6. dtT = softplus(dt_proj_w @ dt_r^T + b[m])  -> [DI][BL] per dir
    for (int dir = 0; dir < 2; dir++)
        gemm_k<4><<<dim3(BL / 64, DI_ / 64), 256, 0, stream>>>(
            dtpw, DTR_, dblb + (size_t)dir * BL * 64, 64,
            dtT + (size_t)dir * (size_t)DI_ * BL, dtpb, nullptr, DI_, BL, DTR_);
    // 7. chunked selective scan (both dirs) -> yT
    scan_kernel<<<dim3(DI_, B_, 2), 256, 0, stream>>>(dtT, xcT, dblb, A_log, Dp, yT);
    // 8. ycomb = (yT0 + yT1)^T * silu(z)
    combine_kernel<<<dim3(DI_ / 32, BL / 32), 256, 0, stream>>>(yT, xz, ycomb);
    // 9. mo_raw = ycomb @ out_proj_w^T (2048 x 512)
    gemm_k<0><<<dim3(DM_ / 64, BL / 64), 256, 0, stream>>>(
        ycomb, DI_, outpw, DI_, moraw, nullptr, nullptr, BL, DM_, DI_);
    // 10. mo_n = LN(mo_raw * mask)
    ln_kernel<<<dim3(BL / 4), 256, 0, stream>>>(moraw, n2w, n2b, mask, xn);
    // 11. h = selu(mo_n @ ff1_w^T + b)  (2048 x 2048), reuse xz
    gemm_k<2><<<dim3(2048 / 64, BL / 64), 256, 0, stream>>>(
        xn, DM_, ff1w, DM_, xz, ff1b, nullptr, BL, 4 * DM_, DM_);
    // 12. out = h @ ff2_w^T + b + x  -> f32 d_out
    gemm_k<3><<<dim3(DM_ / 64, BL / 64), 256, 0, stream>>>(
        xz, 4 * DM_, ff2w, 4 * DM_, (float*)d_out, ff2b, x, BL, DM_, 4 * DM_);
}

// Round 4
// 387.881 us; speedup vs baseline: 2.3740x; 1.4469x over previous
//
#include <hip/hip_runtime.h>
#include <hip/hip_bf16.h>

typedef __hip_bfloat16 bf16;

#define B_   2
#define L_   1024
#define DM_  512
#define DI_  1024
#define N_   16
#define K_   12
#define DTR_ 32

static constexpr int BLD  = B_ * L_ * DI_;   // 2097152
static constexpr int BL   = B_ * L_;         // 2048

using bf16x8 = __attribute__((ext_vector_type(8))) short;
using f32x4  = __attribute__((ext_vector_type(4))) float;

__device__ __forceinline__ float siluf(float x) { return x / (1.f + __expf(-x)); }
__device__ __forceinline__ float softplusf(float x) {
    return fmaxf(x, 0.f) + log1pf(expf(-fabsf(x)));
}
__device__ __forceinline__ float seluf(float x) {
    const float lam = 1.0507009873554805f, alp = 1.6732632423543772f;
    return x > 0.f ? lam * x : lam * alp * (expf(x) - 1.f);
}

// ---------------- weight cast f32 -> bf16 (6 segments, vec4) ----------------
// seg sizes (vec4): inpw 262144 | xpw 16384 | dtpw 8192 | outpw 131072 | ff1w 262144 | ff2w 262144
__global__ __launch_bounds__(256) void cast_w(
    const float* __restrict__ s0, const float* __restrict__ s1, const float* __restrict__ s2,
    const float* __restrict__ s3, const float* __restrict__ s4, const float* __restrict__ s5,
    bf16* __restrict__ dst)
{
    int i = blockIdx.x * 256 + threadIdx.x;   // total 942080
    const float* src; int off;
    if (i < 262144)      { src = s0; off = i; }
    else if (i < 278528) { src = s1; off = i - 262144; }
    else if (i < 286720) { src = s2; off = i - 278528; }
    else if (i < 417792) { src = s3; off = i - 286720; }
    else if (i < 679936) { src = s4; off = i - 417792; }
    else                 { src = s5; off = i - 679936; }
    float4 v = ((const float4*)src)[off];
    bf16* d = dst + (size_t)i * 4;
    d[0] = __float2bfloat16(v.x); d[1] = __float2bfloat16(v.y);
    d[2] = __float2bfloat16(v.z); d[3] = __float2bfloat16(v.w);
}

// ---------------- LayerNorm: one wave per row of 512, bf16 out ----------------
__global__ __launch_bounds__(256) void ln_kernel(
    const float* __restrict__ x, const float* __restrict__ w, const float* __restrict__ b,
    const float* __restrict__ mask, bf16* __restrict__ y)
{
    int row  = blockIdx.x * 4 + (threadIdx.x >> 6);
    int lane = threadIdx.x & 63;
    const float* xr = x + (size_t)row * DM_;
    float mval = mask ? mask[row] : 1.0f;
    float v[8];
    float s = 0.f, ss = 0.f;
#pragma unroll
    for (int i = 0; i < 8; i++) {
        v[i] = xr[lane + i * 64] * mval;
        s += v[i]; ss += v[i] * v[i];
    }
#pragma unroll
    for (int o = 32; o >= 1; o >>= 1) { s += __shfl_xor(s, o); ss += __shfl_xor(ss, o); }
    float mean = s * (1.f / DM_);
    float var  = ss * (1.f / DM_) - mean * mean;
    float r    = rsqrtf(var + 1e-5f);
    bf16* yr = y + (size_t)row * DM_;
#pragma unroll
    for (int i = 0; i < 8; i++) {
        int c = lane + i * 64;
        yr[c] = __float2bfloat16((v[i] - mean) * r * w[c] + b[c]);
    }
}

// ---------------- MFMA GEMM: C(M,N) = A(M,K) @ W(N,K)^T  (bf16 in, fp32 acc) ----------------
// MODE 0: plain  1: bias[n]+softplus  2: bias[n]+selu  3: bias[n]+resid  4: bias[m]+softplus
template<int MODE>
__global__ __launch_bounds__(256) void mgemm_k(
    const short* __restrict__ A, int lda,
    const short* __restrict__ W, int ldw,
    float* __restrict__ C, bf16* __restrict__ Cb,
    const float* __restrict__ bias, const float* __restrict__ resid,
    int M, int N, int Kd)
{
    constexpr int SP = 40;                    // padded LDS row stride (bf16 elems)
    __shared__ short As[128 * SP];
    __shared__ short Ws[128 * SP];
    int bm = blockIdx.y * 128, bn = blockIdx.x * 128;
    int tid = threadIdx.x;
    int lane = tid & 63, w = tid >> 6;
    int wm = (w >> 1) * 64, wn = (w & 1) * 64;
    int l15 = lane & 15, l4 = lane >> 4;
    f32x4 acc[4][4] = {};
    int srow = tid >> 2, scolg = (tid & 3) * 8;
    for (int k0 = 0; k0 < Kd; k0 += 32) {
        int wr0 = bn + srow;      if (wr0 > N - 1) wr0 = N - 1;
        int wr1 = bn + srow + 64; if (wr1 > N - 1) wr1 = N - 1;
        *(bf16x8*)&As[srow * SP + scolg]        = *(const bf16x8*)(A + (size_t)(bm + srow) * lda + k0 + scolg);
        *(bf16x8*)&As[(srow + 64) * SP + scolg] = *(const bf16x8*)(A + (size_t)(bm + srow + 64) * lda + k0 + scolg);
        *(bf16x8*)&Ws[srow * SP + scolg]        = *(const bf16x8*)(W + (size_t)wr0 * ldw + k0 + scolg);
        *(bf16x8*)&Ws[(srow + 64) * SP + scolg] = *(const bf16x8*)(W + (size_t)wr1 * ldw + k0 + scolg);
        __syncthreads();
        bf16x8 af[4], bfr[4];
#pragma unroll
        for (int m = 0; m < 4; m++)
            af[m] = *(const bf16x8*)&As[(wm + m * 16 + l15) * SP + l4 * 8];
#pragma unroll
        for (int n = 0; n < 4; n++)
            bfr[n] = *(const bf16x8*)&Ws[(wn + n * 16 + l15) * SP + l4 * 8];
#pragma unroll
        for (int m = 0; m < 4; m++)
#pragma unroll
            for (int n = 0; n < 4; n++)
                acc[m][n] = __builtin_amdgcn_mfma_f32_16x16x32_bf16(af[m], bfr[n], acc[m][n], 0, 0, 0);
        __syncthreads();
    }
#pragma unroll
    for (int m = 0; m < 4; m++) {
        int row0 = bm + wm + m * 16 + l4 * 4;
#pragma unroll
        for (int n = 0; n < 4; n++) {
            int col = bn + wn + n * 16 + l15;
            if (col < N) {
#pragma unroll
                for (int j = 0; j < 4; j++) {
                    int row = row0 + j;
                    float v = acc[m][n][j];
                    if (MODE == 1) v = softplusf(v + bias[col]);
                    if (MODE == 2) v = seluf(v + bias[col]);
                    if (MODE == 3) v = v + bias[col] + resid[(size_t)row * N + col];
                    if (MODE == 4) v = softplusf(v + bias[row]);
                    if (C)  C[(size_t)row * N + col] = v;
                    if (Cb) Cb[(size_t)row * N + col] = __float2bfloat16(v);
                }
            }
        }
    }
}

// ---------------- depthwise conv (dir0 causal / dir1 anti-causal) + SiLU -> bf16 ----------------
__global__ __launch_bounds__(256) void conv_silu_kernel(
    const float* __restrict__ xz, const float* __restrict__ cw,
    const float* __restrict__ cb, bf16* __restrict__ xcb)
{
    int dir = blockIdx.y;
    int idx = blockIdx.x * 256 + threadIdx.x;   // over B*L*DI
    int d = idx & (DI_ - 1);
    int l = (idx >> 10) & (L_ - 1);
    int b = idx >> 20;
    float acc = cb[d];
#pragma unroll
    for (int k = 0; k < K_; k++) {
        int ls = (dir == 0) ? (l - (K_ - 1) + k) : (l + (K_ - 1) - k);
        if (ls >= 0 && ls < L_)
            acc = fmaf(cw[d * K_ + k], xz[((size_t)(b * L_ + ls)) * (2 * DI_) + d], acc);
    }
    xcb[(size_t)dir * BLD + idx] = __float2bfloat16(siluf(acc));
}

// ---------------- transpose bf16[2][BL][DI] -> f32[2][DI][BL] ----------------
__global__ __launch_bounds__(256) void transpose_kernel(
    const bf16* __restrict__ in, float* __restrict__ out)
{
    __shared__ float tile[32][33];
    int dir = blockIdx.z;
    int d0 = blockIdx.x * 32, l0 = blockIdx.y * 32;
    const bf16* ip = in + (size_t)dir * BLD;
    float* op = out + (size_t)dir * BLD;
    int tx = threadIdx.x & 31, ty = threadIdx.x >> 5;
#pragma unroll
    for (int r = 0; r < 4; r++) {
        int l = l0 + ty * 4 + r;
        tile[ty * 4 + r][tx] = __bfloat162float(ip[(size_t)l * DI_ + d0 + tx]);
    }
    __syncthreads();
#pragma unroll
    for (int r = 0; r < 4; r++) {
        int d = d0 + ty * 4 + r;
        op[(size_t)d * BL + l0 + tx] = tile[tx][ty * 4 + r];
    }
}

// ---------------- chunked selective scan (one dir per launch; dir1 accumulates) ----------------
__global__ __launch_bounds__(256) void scan_kernel(
    const float* __restrict__ dtT,   // [2][DI][BL]
    const float* __restrict__ xcT,   // [2][DI][BL]
    const float* __restrict__ dbl,   // [2][BL][64]
    const float* __restrict__ A_log, const float* __restrict__ Dp,
    float* __restrict__ yT,          // [DI][BL] (sum over dirs)
    int dir, int accum)
{
    __shared__ float sA[16][16];
    __shared__ float sB[16][16];
    __shared__ float sY[1024];
    int d = blockIdx.x, b = blockIdx.y;
    int tid = threadIdx.x, n = tid & 15, c = tid >> 4;
    size_t row = ((size_t)dir * DI_ + d) * BL + (size_t)b * L_;
    const float* dtp = dtT + row;
    const float* xcp = xcT + row;
    const float* dblp = dbl + ((size_t)dir * BL + (size_t)b * L_) * 64;
    float Aval = -__expf(A_log[d * N_ + n]);
    float Dd = Dp[d];
    int l0 = c * 64;
    float acum = 1.f, h = 0.f;
    for (int j = 0; j < 64; j += 4) {
        float4 dt4 = *(const float4*)(dtp + l0 + j);
        float4 xc4 = *(const float4*)(xcp + l0 + j);
#pragma unroll
        for (int q = 0; q < 4; q++) {
            float dtv = ((const float*)&dt4)[q];
            float xcv = ((const float*)&xc4)[q];
            float Bv = dblp[(l0 + j + q) * 64 + DTR_ + n];
            float a = __expf(dtv * Aval);
            acum *= a;
            h = fmaf(a, h, dtv * Bv * xcv);
        }
    }
    sA[c][n] = acum;
    sB[c][n] = h;
    __syncthreads();
    float hp = 0.f;
    for (int cc = 0; cc < c; cc++) hp = fmaf(sA[cc][n], hp, sB[cc][n]);
    h = hp;
    for (int j = 0; j < 64; j += 4) {
        float4 dt4 = *(const float4*)(dtp + l0 + j);
        float4 xc4 = *(const float4*)(xcp + l0 + j);
#pragma unroll
        for (int q = 0; q < 4; q++) {
            int l = l0 + j + q;
            float dtv = ((const float*)&dt4)[q];
            float xcv = ((const float*)&xc4)[q];
            float Bv = dblp[l * 64 + DTR_ + n];
            float Cv = dblp[l * 64 + DTR_ + N_ + n];
            float a = __expf(dtv * Aval);
            h = fmaf(a, h, dtv * Bv * xcv);
            float p = h * Cv;
            p += __shfl_xor(p, 1); p += __shfl_xor(p, 2);
            p += __shfl_xor(p, 4); p += __shfl_xor(p, 8);
            if (n == 0) sY[l] = fmaf(xcv, Dd, p);
        }
    }
    __syncthreads();
    float* yp = yT + (size_t)d * BL + (size_t)b * L_;
#pragma unroll
    for (int i = 0; i < 4; i++) {
        int idx = tid + i * 256;
        if (accum) yp[idx] += sY[idx]; else yp[idx] = sY[idx];
    }
}

// ---------------- combine + transpose: ycomb_b[bl][d] = yT[d][bl] * silu(z) ----------------
__global__ __launch_bounds__(256) void combine_kernel(
    const float* __restrict__ yT, const float* __restrict__ xz,
    bf16* __restrict__ yc)
{
    __shared__ float tile[32][33];
    int d0 = blockIdx.x * 32, bl0 = blockIdx.y * 32;
    int tx = threadIdx.x & 31, ty = threadIdx.x >> 5;
#pragma unroll
    for (int r = 0; r < 4; r++) {
        int d = d0 + ty * 4 + r;
        tile[ty * 4 + r][tx] = yT[(size_t)d * BL + bl0 + tx];
    }
    __syncthreads();
#pragma unroll
    for (int r = 0; r < 4; r++) {
        int bl = bl0 + ty * 4 + r;
        float z = xz[(size_t)bl * (2 * DI_) + DI_ + d0 + tx];
        yc[(size_t)bl * DI_ + d0 + tx] = __float2bfloat16(tile[tx][ty * 4 + r] * siluf(z));
    }
}

extern "C" void kernel_launch(void* const* d_in, const int* in_sizes, int n_in,
                              void* d_out, int out_size, void* d_ws, size_t ws_size,
                              hipStream_t stream) {
    const float* x     = (const float*)d_in[0];
    const float* mask  = (const float*)d_in[1];
    const float* n1w   = (const float*)d_in[2];
    const float* n1b   = (const float*)d_in[3];
    const float* n2w   = (const float*)d_in[4];
    const float* n2b   = (const float*)d_in[5];
    const float* ff1w  = (const float*)d_in[6];
    const float* ff1b  = (const float*)d_in[7];
    const float* ff2w  = (const float*)d_in[8];
    const float* ff2b  = (const float*)d_in[9];
    const float* inpw  = (const float*)d_in[10];
    const float* convw = (const float*)d_in[11];
    const float* convb = (const float*)d_in[12];
    const float* xpw   = (const float*)d_in[13];
    const float* dtpw  = (const float*)d_in[14];
    const float *A_log, *Dp, *outpw, *dtpb;
    if (in_sizes[15] == DI_ * N_) {
        A_log = (const float*)d_in[15]; Dp = (const float*)d_in[16];
        outpw = (const float*)d_in[17]; dtpb = (const float*)d_in[18];
    } else {
        dtpb = (const float*)d_in[15]; A_log = (const float*)d_in[16];
        Dp = (const float*)d_in[17]; outpw = (const float*)d_in[18];
    }

    float* ws = (float*)d_ws;
    // float-unit offsets
    bf16*  wb      = (bf16*)ws;                         // 3768320 bf16 = 1884160 units
    float* xz      = ws + 1884160;                      // 4194304
    bf16*  xn_b    = (bf16*)(ws + 6078464);             // 524288 units (also mon_b)
    bf16*  xc_b    = (bf16*)(ws + 6602752);             // 2097152 units (also h_b)
    float* xcT     = ws + 8699904;                      // 4194304
    float* dblb    = ws + 12894208;                     // 262144
    bf16*  dbl_b   = (bf16*)(ws + 13156352);            // 131072 units
    float* dtT     = ws + 13287424;                     // 4194304 (also moraw after scan)
    float* yT      = ws + 17481728;                     // 2097152
    bf16*  ycomb_b = (bf16*)(ws + 19578880);            // 1048576 units

    // bf16 weight segment pointers (offsets in bf16 elems)
    bf16* inpw_b = wb;
    bf16* xpw_b  = wb + 1048576;
    bf16* dtpw_b = wb + 1114112;
    bf16* outpw_b= wb + 1146880;
    bf16* ff1w_b = wb + 1671168;
    bf16* ff2w_b = wb + 2719744;
    bf16* mon_b  = xn_b;
    bf16* h_b    = xc_b;
    float* moraw = dtT;

    // 0. cast weights to bf16
    cast_w<<<dim3(3680), 256, 0, stream>>>(inpw, xpw, dtpw, outpw, ff1w, ff2w, wb);
    // 1. xn = LN(x) -> bf16
    ln_kernel<<<dim3(BL / 4), 256, 0, stream>>>(x, n1w, n1b, nullptr, xn_b);
    // 2. xz = xn @ in_proj_w^T (2048x2048x512)
    mgemm_k<0><<<dim3(16, 16), 256, 0, stream>>>(
        (const short*)xn_b, DM_, (const short*)inpw_b, DM_, xz, nullptr,
        nullptr, nullptr, BL, 2 * DI_, DM_);
    // 3. conv + silu -> bf16
    conv_silu_kernel<<<dim3(BLD / 256, 2), 256, 0, stream>>>(xz, convw, convb, xc_b);
    // 4. xcT = f32 transpose(xc_b)
    transpose_kernel<<<dim3(DI_ / 32, BL / 32, 2), 256, 0, stream>>>(xc_b, xcT);
    // 5. dbl = xc @ x_proj_w^T  (4096x64x1024, both dirs at once)
    mgemm_k<0><<<dim3(1, 32), 256, 0, stream>>>(
        (const short*)xc_b, DI_, (const short*)xpw_b, DI_, dblb, dbl_b,
        nullptr, nullptr, 2 * BL, 64, DI_);
    // 6. dtT = softplus(dt_proj_w @ dt_r^T + b[m]) -> [DI][BL] per dir
    for (int dir = 0; dir < 2; dir++)
        mgemm_k<4><<<dim3(16, 8), 256, 0, stream>>>(
            (const short*)dtpw_b, DTR_, (const short*)(dbl_b + (size_t)dir * BL * 64), 64,
            dtT + (size_t)dir * (size_t)DI_ * BL, nullptr, dtpb, nullptr, DI_, BL, DTR_);
    // 7. chunked scan: dir0 writes, dir1 accumulates
    scan_kernel<<<dim3(DI_, B_), 256, 0, stream>>>(dtT, xcT, dblb, A_log, Dp, yT, 0, 0);
    scan_kernel<<<dim3(DI_, B_), 256, 0, stream>>>(dtT, xcT, dblb, A_log, Dp, yT, 1, 1);
    // 8. ycomb_b = yT^T * silu(z) -> bf16
    combine_kernel<<<dim3(DI_ / 32, BL / 32), 256, 0, stream>>>(yT, xz, ycomb_b);
    // 9. mo_raw = ycomb @ out_proj_w^T (2048x512x1024)
    mgemm_k<0><<<dim3(4, 16), 256, 0, stream>>>(
        (const short*)ycomb_b, DI_, (const short*)outpw_b, DI_, moraw, nullptr,
        nullptr, nullptr, BL, DM_, DI_);
    // 10. mo_n = LN(mo_raw * mask) -> bf16
    ln_kernel<<<dim3(BL / 4), 256, 0, stream>>>(moraw, n2w, n2b, mask, mon_b);
    // 11. h = selu(mo_n @ ff1_w^T + b) -> bf16 (2048x2048x512)
    mgemm_k<2><<<dim3(16, 16), 256, 0, stream>>>(
        (const short*)mon_b, DM_, (const short*)ff1w_b, DM_, nullptr, h_b,
        ff1b, nullptr, BL, 4 * DM_, DM_);
    // 12. out = h @ ff2_w^T + b + x (2048x512x2048) -> f32 d_out
    mgemm_k<3><<<dim3(4, 16), 256, 0, stream>>>(
        (const short*)h_b, 4 * DM_, (const short*)ff2w_b, 4 * DM_, (float*)d_out, nullptr,
        ff2b, x, BL, DM_, 4 * DM_);
}

// Round 5
// 274.108 us; speedup vs baseline: 3.3594x; 1.4151x over previous
//
#include <hip/hip_runtime.h>
#include <hip/hip_bf16.h>

typedef __hip_bfloat16 bf16;

#define B_   2
#define L_   1024
#define DM_  512
#define DI_  1024
#define N_   16
#define K_   12
#define DTR_ 32

static constexpr int BLD  = B_ * L_ * DI_;   // 2097152
static constexpr int BL   = B_ * L_;         // 2048

using bf16x8 = __attribute__((ext_vector_type(8))) short;
using f32x4  = __attribute__((ext_vector_type(4))) float;

__device__ __forceinline__ float siluf(float x) { return x / (1.f + __expf(-x)); }
__device__ __forceinline__ float softplusf(float x) {
    return fmaxf(x, 0.f) + log1pf(expf(-fabsf(x)));
}
__device__ __forceinline__ float seluf(float x) {
    const float lam = 1.0507009873554805f, alp = 1.6732632423543772f;
    return x > 0.f ? lam * x : lam * alp * (expf(x) - 1.f);
}

// ---------------- weight cast f32 -> bf16 (6 segments, vec4) ----------------
__global__ __launch_bounds__(256) void cast_w(
    const float* __restrict__ s0, const float* __restrict__ s1, const float* __restrict__ s2,
    const float* __restrict__ s3, const float* __restrict__ s4, const float* __restrict__ s5,
    bf16* __restrict__ dst)
{
    int i = blockIdx.x * 256 + threadIdx.x;   // total 942080 vec4
    const float* src; int off;
    if (i < 262144)      { src = s0; off = i; }
    else if (i < 278528) { src = s1; off = i - 262144; }
    else if (i < 286720) { src = s2; off = i - 278528; }
    else if (i < 417792) { src = s3; off = i - 286720; }
    else if (i < 679936) { src = s4; off = i - 417792; }
    else                 { src = s5; off = i - 679936; }
    float4 v = ((const float4*)src)[off];
    bf16* d = dst + (size_t)i * 4;
    d[0] = __float2bfloat16(v.x); d[1] = __float2bfloat16(v.y);
    d[2] = __float2bfloat16(v.z); d[3] = __float2bfloat16(v.w);
}

// ---------------- LayerNorm: one wave per row of 512, bf16 out ----------------
__global__ __launch_bounds__(256) void ln_kernel(
    const float* __restrict__ x, const float* __restrict__ w, const float* __restrict__ b,
    const float* __restrict__ mask, bf16* __restrict__ y)
{
    int row  = blockIdx.x * 4 + (threadIdx.x >> 6);
    int lane = threadIdx.x & 63;
    const float* xr = x + (size_t)row * DM_;
    float mval = mask ? mask[row] : 1.0f;
    float v[8];
    float s = 0.f, ss = 0.f;
#pragma unroll
    for (int i = 0; i < 8; i++) {
        v[i] = xr[lane + i * 64] * mval;
        s += v[i]; ss += v[i] * v[i];
    }
#pragma unroll
    for (int o = 32; o >= 1; o >>= 1) { s += __shfl_xor(s, o); ss += __shfl_xor(ss, o); }
    float mean = s * (1.f / DM_);
    float var  = ss * (1.f / DM_) - mean * mean;
    float r    = rsqrtf(var + 1e-5f);
    bf16* yr = y + (size_t)row * DM_;
#pragma unroll
    for (int i = 0; i < 8; i++) {
        int c = lane + i * 64;
        yr[c] = __float2bfloat16((v[i] - mean) * r * w[c] + b[c]);
    }
}

// ---------------- MFMA GEMM: C(M,N) = A(M,K) @ W(N,K)^T  (bf16 in, fp32 acc) ----------------
// 64x64 tile, 4 waves (2x2), each wave 32x32 via 2x2 mfma_f32_16x16x32_bf16.
// KS>1: write fp32 partials P[blockIdx.z][M][N] (no epilogue).
// KS==1 MODE: 0 plain  2 bias[n]+selu  4 bias[m]+softplus
template<int MODE, int BK, int KS>
__global__ __launch_bounds__(256) void mgemm_k(
    const short* __restrict__ A, int lda,
    const short* __restrict__ W, int ldw,
    float* __restrict__ C, bf16* __restrict__ Cb,
    const float* __restrict__ bias,
    int M, int N, int Kd)
{
    constexpr int SP = BK + 8;                // padded LDS row stride (bf16 elems)
    __shared__ short As[64 * SP];
    __shared__ short Ws[64 * SP];
    int bm = blockIdx.y * 64, bn = blockIdx.x * 64;
    int tid = threadIdx.x;
    int lane = tid & 63, w = tid >> 6;
    int wm = (w >> 1) * 32, wn = (w & 1) * 32;
    int l15 = lane & 15, l4 = lane >> 4;
    f32x4 acc[2][2] = {};
    int srow = tid >> 2;
    int scol = (tid & 3) * (BK / 4);
    int kbeg = (KS > 1) ? blockIdx.z * (Kd / KS) : 0;
    int kend = (KS > 1) ? kbeg + Kd / KS : Kd;
    const short* Ap = A + (size_t)(bm + srow) * lda + scol;
    const short* Wp = W + (size_t)(bn + srow) * ldw + scol;
    short* Asw = &As[srow * SP + scol];
    short* Wsw = &Ws[srow * SP + scol];
    for (int k0 = kbeg; k0 < kend; k0 += BK) {
#pragma unroll
        for (int i = 0; i < BK / 32; i++) {
            *(bf16x8*)(Asw + i * 8) = *(const bf16x8*)(Ap + k0 + i * 8);
            *(bf16x8*)(Wsw + i * 8) = *(const bf16x8*)(Wp + k0 + i * 8);
        }
        __syncthreads();
#pragma unroll
        for (int ks = 0; ks < BK / 32; ks++) {
            bf16x8 af[2], bfr[2];
#pragma unroll
            for (int mi = 0; mi < 2; mi++)
                af[mi] = *(const bf16x8*)&As[(wm + mi * 16 + l15) * SP + ks * 32 + l4 * 8];
#pragma unroll
            for (int ni = 0; ni < 2; ni++)
                bfr[ni] = *(const bf16x8*)&Ws[(wn + ni * 16 + l15) * SP + ks * 32 + l4 * 8];
#pragma unroll
            for (int mi = 0; mi < 2; mi++)
#pragma unroll
                for (int ni = 0; ni < 2; ni++)
                    acc[mi][ni] = __builtin_amdgcn_mfma_f32_16x16x32_bf16(af[mi], bfr[ni], acc[mi][ni], 0, 0, 0);
        }
        __syncthreads();
    }
    if (KS > 1) {
        float* P = C + (size_t)blockIdx.z * M * N;
#pragma unroll
        for (int mi = 0; mi < 2; mi++) {
            int row0 = bm + wm + mi * 16 + l4 * 4;
#pragma unroll
            for (int ni = 0; ni < 2; ni++) {
                int col = bn + wn + ni * 16 + l15;
#pragma unroll
                for (int j = 0; j < 4; j++)
                    P[(size_t)(row0 + j) * N + col] = acc[mi][ni][j];
            }
        }
    } else {
#pragma unroll
        for (int mi = 0; mi < 2; mi++) {
            int row0 = bm + wm + mi * 16 + l4 * 4;
#pragma unroll
            for (int ni = 0; ni < 2; ni++) {
                int col = bn + wn + ni * 16 + l15;
#pragma unroll
                for (int j = 0; j < 4; j++) {
                    int row = row0 + j;
                    float v = acc[mi][ni][j];
                    if (MODE == 2) v = seluf(v + bias[col]);
                    if (MODE == 4) v = softplusf(v + bias[row]);
                    if (C)  C[(size_t)row * N + col] = v;
                    if (Cb) Cb[(size_t)row * N + col] = __float2bfloat16(v);
                }
            }
        }
    }
}

// ---------------- split-K reduce: sum KS partial slices (+ optional bias/resid) ----------------
// RMODE 0: plain (f32 and/or bf16 out)   1: + bias[col] + resid (f32 out)
template<int KS, int RMODE>
__global__ __launch_bounds__(256) void reduce_k(
    const float* __restrict__ P, float* __restrict__ C, bf16* __restrict__ Cb,
    const float* __restrict__ bias, const float* __restrict__ resid,
    int MN, int N)
{
    int i = (blockIdx.x * 256 + threadIdx.x) * 4;
    float4 v = *(const float4*)(P + i);
#pragma unroll
    for (int s = 1; s < KS; s++) {
        float4 u = *(const float4*)(P + (size_t)s * MN + i);
        v.x += u.x; v.y += u.y; v.z += u.z; v.w += u.w;
    }
    if (RMODE == 1) {
        float4 bz = *(const float4*)(bias + (i % N));
        float4 rx = *(const float4*)(resid + i);
        v.x += bz.x + rx.x; v.y += bz.y + rx.y;
        v.z += bz.z + rx.z; v.w += bz.w + rx.w;
    }
    if (C) *(float4*)(C + i) = v;
    if (Cb) {
        bf16* d = Cb + i;
        d[0] = __float2bfloat16(v.x); d[1] = __float2bfloat16(v.y);
        d[2] = __float2bfloat16(v.z); d[3] = __float2bfloat16(v.w);
    }
}

// ---------------- depthwise conv (dir0 causal / dir1 anti-causal) + SiLU -> bf16 ----------------
__global__ __launch_bounds__(256) void conv_silu_kernel(
    const float* __restrict__ xz, const float* __restrict__ cw,
    const float* __restrict__ cb, bf16* __restrict__ xcb)
{
    int dir = blockIdx.y;
    int idx = blockIdx.x * 256 + threadIdx.x;   // over B*L*DI
    int d = idx & (DI_ - 1);
    int l = (idx >> 10) & (L_ - 1);
    int b = idx >> 20;
    float acc = cb[d];
#pragma unroll
    for (int k = 0; k < K_; k++) {
        int ls = (dir == 0) ? (l - (K_ - 1) + k) : (l + (K_ - 1) - k);
        if (ls >= 0 && ls < L_)
            acc = fmaf(cw[d * K_ + k], xz[((size_t)(b * L_ + ls)) * (2 * DI_) + d], acc);
    }
    xcb[(size_t)dir * BLD + idx] = __float2bfloat16(siluf(acc));
}

// ---------------- transpose bf16[2][BL][DI] -> f32[2][DI][BL] ----------------
__global__ __launch_bounds__(256) void transpose_kernel(
    const bf16* __restrict__ in, float* __restrict__ out)
{
    __shared__ float tile[32][33];
    int dir = blockIdx.z;
    int d0 = blockIdx.x * 32, l0 = blockIdx.y * 32;
    const bf16* ip = in + (size_t)dir * BLD;
    float* op = out + (size_t)dir * BLD;
    int tx = threadIdx.x & 31, ty = threadIdx.x >> 5;
#pragma unroll
    for (int r = 0; r < 4; r++) {
        int l = l0 + ty * 4 + r;
        tile[ty * 4 + r][tx] = __bfloat162float(ip[(size_t)l * DI_ + d0 + tx]);
    }
    __syncthreads();
#pragma unroll
    for (int r = 0; r < 4; r++) {
        int d = d0 + ty * 4 + r;
        op[(size_t)d * BL + l0 + tx] = tile[tx][ty * 4 + r];
    }
}

// ---------------- chunked selective scan (one dir per launch; dir1 accumulates) ----------------
__global__ __launch_bounds__(256) void scan_kernel(
    const float* __restrict__ dtT,   // [2][DI][BL]
    const float* __restrict__ xcT,   // [2][DI][BL]
    const float* __restrict__ dbl,   // [2][BL][64]
    const float* __restrict__ A_log, const float* __restrict__ Dp,
    float* __restrict__ yT,          // [DI][BL] (sum over dirs)
    int dir, int accum)
{
    __shared__ float sA[16][16];
    __shared__ float sB[16][16];
    __shared__ float sY[1024];
    int d = blockIdx.x, b = blockIdx.y;
    int tid = threadIdx.x, n = tid & 15, c = tid >> 4;
    size_t row = ((size_t)dir * DI_ + d) * BL + (size_t)b * L_;
    const float* dtp = dtT + row;
    const float* xcp = xcT + row;
    const float* dblp = dbl + ((size_t)dir * BL + (size_t)b * L_) * 64;
    float Aval = -__expf(A_log[d * N_ + n]);
    float Dd = Dp[d];
    int l0 = c * 64;
    float acum = 1.f, h = 0.f;
    for (int j = 0; j < 64; j += 4) {
        float4 dt4 = *(const float4*)(dtp + l0 + j);
        float4 xc4 = *(const float4*)(xcp + l0 + j);
#pragma unroll
        for (int q = 0; q < 4; q++) {
            float dtv = ((const float*)&dt4)[q];
            float xcv = ((const float*)&xc4)[q];
            float Bv = dblp[(l0 + j + q) * 64 + DTR_ + n];
            float a = __expf(dtv * Aval);
            acum *= a;
            h = fmaf(a, h, dtv * Bv * xcv);
        }
    }
    sA[c][n] = acum;
    sB[c][n] = h;
    __syncthreads();
    float hp = 0.f;
    for (int cc = 0; cc < c; cc++) hp = fmaf(sA[cc][n], hp, sB[cc][n]);
    h = hp;
    for (int j = 0; j < 64; j += 4) {
        float4 dt4 = *(const float4*)(dtp + l0 + j);
        float4 xc4 = *(const float4*)(xcp + l0 + j);
#pragma unroll
        for (int q = 0; q < 4; q++) {
            int l = l0 + j + q;
            float dtv = ((const float*)&dt4)[q];
            float xcv = ((const float*)&xc4)[q];
            float Bv = dblp[l * 64 + DTR_ + n];
            float Cv = dblp[l * 64 + DTR_ + N_ + n];
            float a = __expf(dtv * Aval);
            h = fmaf(a, h, dtv * Bv * xcv);
            float p = h * Cv;
            p += __shfl_xor(p, 1); p += __shfl_xor(p, 2);
            p += __shfl_xor(p, 4); p += __shfl_xor(p, 8);
            if (n == 0) sY[l] = fmaf(xcv, Dd, p);
        }
    }
    __syncthreads();
    float* yp = yT + (size_t)d * BL + (size_t)b * L_;
#pragma unroll
    for (int i = 0; i < 4; i++) {
        int idx = tid + i * 256;
        if (accum) yp[idx] += sY[idx]; else yp[idx] = sY[idx];
    }
}

// ---------------- combine + transpose: ycomb_b[bl][d] = yT[d][bl] * silu(z) ----------------
__global__ __launch_bounds__(256) void combine_kernel(
    const float* __restrict__ yT, const float* __restrict__ xz,
    bf16* __restrict__ yc)
{
    __shared__ float tile[32][33];
    int d0 = blockIdx.x * 32, bl0 = blockIdx.y * 32;
    int tx = threadIdx.x & 31, ty = threadIdx.x >> 5;
#pragma unroll
    for (int r = 0; r < 4; r++) {
        int d = d0 + ty * 4 + r;
        tile[ty * 4 + r][tx] = yT[(size_t)d * BL + bl0 + tx];
    }
    __syncthreads();
#pragma unroll
    for (int r = 0; r < 4; r++) {
        int bl = bl0 + ty * 4 + r;
        float z = xz[(size_t)bl * (2 * DI_) + DI_ + d0 + tx];
        yc[(size_t)bl * DI_ + d0 + tx] = __float2bfloat16(tile[tx][ty * 4 + r] * siluf(z));
    }
}

extern "C" void kernel_launch(void* const* d_in, const int* in_sizes, int n_in,
                              void* d_out, int out_size, void* d_ws, size_t ws_size,
                              hipStream_t stream) {
    const float* x     = (const float*)d_in[0];
    const float* mask  = (const float*)d_in[1];
    const float* n1w   = (const float*)d_in[2];
    const float* n1b   = (const float*)d_in[3];
    const float* n2w   = (const float*)d_in[4];
    const float* n2b   = (const float*)d_in[5];
    const float* ff1w  = (const float*)d_in[6];
    const float* ff1b  = (const float*)d_in[7];
    const float* ff2w  = (const float*)d_in[8];
    const float* ff2b  = (const float*)d_in[9];
    const float* inpw  = (const float*)d_in[10];
    const float* convw = (const float*)d_in[11];
    const float* convb = (const float*)d_in[12];
    const float* xpw   = (const float*)d_in[13];
    const float* dtpw  = (const float*)d_in[14];
    const float *A_log, *Dp, *outpw, *dtpb;
    if (in_sizes[15] == DI_ * N_) {
        A_log = (const float*)d_in[15]; Dp = (const float*)d_in[16];
        outpw = (const float*)d_in[17]; dtpb = (const float*)d_in[18];
    } else {
        dtpb = (const float*)d_in[15]; A_log = (const float*)d_in[16];
        Dp = (const float*)d_in[17]; outpw = (const float*)d_in[18];
    }

    float* ws = (float*)d_ws;
    // float-unit offsets (same proven footprint as R4)
    bf16*  wb      = (bf16*)ws;                         // 1884160 fu
    float* xz      = ws + 1884160;                      // 4194304 fu (also P9/P12 partials)
    bf16*  xn_b    = (bf16*)(ws + 6078464);             // 524288 fu (also mon_b)
    bf16*  xc_b    = (bf16*)(ws + 6602752);             // 2097152 fu (also h_b)
    float* xcT     = ws + 8699904;                      // 4194304 fu
    float* dblb    = ws + 12894208;                     // 262144 fu
    bf16*  dbl_b   = (bf16*)(ws + 13156352);            // 131072 fu
    float* dtT     = ws + 13287424;                     // 4194304 fu (also P5 partials, moraw)
    float* yT      = ws + 17481728;                     // 2097152 fu
    bf16*  ycomb_b = (bf16*)(ws + 19578880);            // 524288 fu

    bf16* inpw_b = wb;
    bf16* xpw_b  = wb + 1048576;
    bf16* dtpw_b = wb + 1114112;
    bf16* outpw_b= wb + 1146880;
    bf16* ff1w_b = wb + 1671168;
    bf16* ff2w_b = wb + 2719744;
    bf16* mon_b  = xn_b;
    bf16* h_b    = xc_b;
    float* moraw = dtT;
    float* P5    = dtT;      // [8][4096][64] fu 2097152 — dead before dtT written
    float* P9    = xz;       // [2][2048][512] fu 2097152 — xz dead after combine
    float* P12   = xz;

    // 0. cast weights to bf16
    cast_w<<<dim3(3680), 256, 0, stream>>>(inpw, xpw, dtpw, outpw, ff1w, ff2w, wb);
    // 1. xn = LN(x) -> bf16
    ln_kernel<<<dim3(BL / 4), 256, 0, stream>>>(x, n1w, n1b, nullptr, xn_b);
    // 2. xz = xn @ in_proj_w^T (2048x2048x512), grid 1024
    mgemm_k<0, 64, 1><<<dim3(32, 32), 256, 0, stream>>>(
        (const short*)xn_b, DM_, (const short*)inpw_b, DM_, xz, nullptr,
        nullptr, BL, 2 * DI_, DM_);
    // 3. conv + silu -> bf16
    conv_silu_kernel<<<dim3(BLD / 256, 2), 256, 0, stream>>>(xz, convw, convb, xc_b);
    // 4. xcT = f32 transpose(xc_b)
    transpose_kernel<<<dim3(DI_ / 32, BL / 32, 2), 256, 0, stream>>>(xc_b, xcT);
    // 5. dbl = xc @ x_proj_w^T (4096x64x1024), split-K 8, grid 512
    mgemm_k<0, 64, 8><<<dim3(1, 64, 8), 256, 0, stream>>>(
        (const short*)xc_b, DI_, (const short*)xpw_b, DI_, P5, nullptr,
        nullptr, 2 * BL, 64, DI_);
    reduce_k<8, 0><<<dim3(256), 256, 0, stream>>>(P5, dblb, dbl_b, nullptr, nullptr,
                                                  2 * BL * 64, 64);
    // 6. dtT = softplus(dt_proj_w @ dt_r^T + b[m]) -> [DI][BL] per dir, grid 512 each
    for (int dir = 0; dir < 2; dir++)
        mgemm_k<4, 32, 1><<<dim3(32, 16), 256, 0, stream>>>(
            (const short*)dtpw_b, DTR_, (const short*)(dbl_b + (size_t)dir * BL * 64), 64,
            dtT + (size_t)dir * (size_t)DI_ * BL, nullptr, dtpb, DI_, BL, DTR_);
    // 7. chunked scan: dir0 writes, dir1 accumulates
    scan_kernel<<<dim3(DI_, B_), 256, 0, stream>>>(dtT, xcT, dblb, A_log, Dp, yT, 0, 0);
    scan_kernel<<<dim3(DI_, B_), 256, 0, stream>>>(dtT, xcT, dblb, A_log, Dp, yT, 1, 1);
    // 8. ycomb_b = yT^T * silu(z) -> bf16
    combine_kernel<<<dim3(DI_ / 32, BL / 32), 256, 0, stream>>>(yT, xz, ycomb_b);
    // 9. mo_raw = ycomb @ out_proj_w^T (2048x512x1024), split-K 2, grid 512
    mgemm_k<0, 64, 2><<<dim3(8, 32, 2), 256, 0, stream>>>(
        (const short*)ycomb_b, DI_, (const short*)outpw_b, DI_, P9, nullptr,
        nullptr, BL, DM_, DI_);
    reduce_k<2, 0><<<dim3(1024), 256, 0, stream>>>(P9, moraw, nullptr, nullptr, nullptr,
                                                   BL * DM_, DM_);
    // 10. mo_n = LN(mo_raw * mask) -> bf16
    ln_kernel<<<dim3(BL / 4), 256, 0, stream>>>(moraw, n2w, n2b, mask, mon_b);
    // 11. h = selu(mo_n @ ff1_w^T + b) -> bf16 (2048x2048x512), grid 1024
    mgemm_k<2, 64, 1><<<dim3(32, 32), 256, 0, stream>>>(
        (const short*)mon_b, DM_, (const short*)ff1w_b, DM_, nullptr, h_b,
        ff1b, BL, 4 * DM_, DM_);
    // 12. out = h @ ff2_w^T (2048x512x2048), split-K 2, grid 512; reduce adds bias + x
    mgemm_k<0, 64, 2><<<dim3(8, 32, 2), 256, 0, stream>>>(
        (const short*)h_b, 4 * DM_, (const short*)ff2w_b, 4 * DM_, P12, nullptr,
        nullptr, BL, DM_, 4 * DM_);
    reduce_k<2, 1><<<dim3(1024), 256, 0, stream>>>(P12, (float*)d_out, nullptr, ff2b, x,
                                                   BL * DM_, DM_);
}

// Round 6
// 237.283 us; speedup vs baseline: 3.8808x; 1.1552x over previous
//
#include <hip/hip_runtime.h>
#include <hip/hip_bf16.h>

typedef __hip_bfloat16 bf16;

#define B_   2
#define L_   1024
#define DM_  512
#define DI_  1024
#define N_   16
#define K_   12
#define DTR_ 32

static constexpr int BLD  = B_ * L_ * DI_;   // 2097152
static constexpr int BL   = B_ * L_;         // 2048

using bf16x8 = __attribute__((ext_vector_type(8))) short;
using f32x4  = __attribute__((ext_vector_type(4))) float;

__device__ __forceinline__ float siluf(float x) { return x / (1.f + __expf(-x)); }
__device__ __forceinline__ float softplusf(float x) {
    return fmaxf(x, 0.f) + log1pf(expf(-fabsf(x)));
}
__device__ __forceinline__ float seluf(float x) {
    const float lam = 1.0507009873554805f, alp = 1.6732632423543772f;
    return x > 0.f ? lam * x : lam * alp * (expf(x) - 1.f);
}
__device__ __forceinline__ ushort bfbits(float x) {
    bf16 v = __float2bfloat16(x);
    return *(ushort*)&v;
}

// ---------------- weight cast f32 -> bf16 (6 segments, vec4) ----------------
__global__ __launch_bounds__(256) void cast_w(
    const float* __restrict__ s0, const float* __restrict__ s1, const float* __restrict__ s2,
    const float* __restrict__ s3, const float* __restrict__ s4, const float* __restrict__ s5,
    bf16* __restrict__ dst)
{
    int i = blockIdx.x * 256 + threadIdx.x;   // total 942080 vec4
    const float* src; int off;
    if (i < 262144)      { src = s0; off = i; }
    else if (i < 278528) { src = s1; off = i - 262144; }
    else if (i < 286720) { src = s2; off = i - 278528; }
    else if (i < 417792) { src = s3; off = i - 286720; }
    else if (i < 679936) { src = s4; off = i - 417792; }
    else                 { src = s5; off = i - 679936; }
    float4 v = ((const float4*)src)[off];
    bf16* d = dst + (size_t)i * 4;
    d[0] = __float2bfloat16(v.x); d[1] = __float2bfloat16(v.y);
    d[2] = __float2bfloat16(v.z); d[3] = __float2bfloat16(v.w);
}

// ---------------- LayerNorm: one wave per row of 512, bf16 out ----------------
__global__ __launch_bounds__(256) void ln_kernel(
    const float* __restrict__ x, const float* __restrict__ w, const float* __restrict__ b,
    const float* __restrict__ mask, bf16* __restrict__ y)
{
    int row  = blockIdx.x * 4 + (threadIdx.x >> 6);
    int lane = threadIdx.x & 63;
    const float* xr = x + (size_t)row * DM_;
    float mval = mask ? mask[row] : 1.0f;
    float v[8];
    float s = 0.f, ss = 0.f;
#pragma unroll
    for (int i = 0; i < 8; i++) {
        v[i] = xr[lane + i * 64] * mval;
        s += v[i]; ss += v[i] * v[i];
    }
#pragma unroll
    for (int o = 32; o >= 1; o >>= 1) { s += __shfl_xor(s, o); ss += __shfl_xor(ss, o); }
    float mean = s * (1.f / DM_);
    float var  = ss * (1.f / DM_) - mean * mean;
    float r    = rsqrtf(var + 1e-5f);
    bf16* yr = y + (size_t)row * DM_;
#pragma unroll
    for (int i = 0; i < 8; i++) {
        int c = lane + i * 64;
        yr[c] = __float2bfloat16((v[i] - mean) * r * w[c] + b[c]);
    }
}

// ---------------- MFMA GEMM: C(M,N) = A(M,K) @ W(N,K)^T  (bf16 in, fp32 acc) ----------------
// 64x64 tile, 4 waves (2x2), each wave 32x32 via 2x2 mfma_f32_16x16x32_bf16.
// KS>1: write fp32 partials P[blockIdx.z][M][N] (no epilogue).
// KS==1 MODE: 0 plain  2 bias[n]+selu  4 bias[m]+softplus
template<int MODE, int BK, int KS>
__global__ __launch_bounds__(256) void mgemm_k(
    const short* __restrict__ A, int lda,
    const short* __restrict__ W, int ldw,
    float* __restrict__ C, bf16* __restrict__ Cb,
    const float* __restrict__ bias,
    int M, int N, int Kd)
{
    constexpr int SP = BK + 8;                // padded LDS row stride (bf16 elems)
    __shared__ short As[64 * SP];
    __shared__ short Ws[64 * SP];
    int bm = blockIdx.y * 64, bn = blockIdx.x * 64;
    int tid = threadIdx.x;
    int lane = tid & 63, w = tid >> 6;
    int wm = (w >> 1) * 32, wn = (w & 1) * 32;
    int l15 = lane & 15, l4 = lane >> 4;
    f32x4 acc[2][2] = {};
    int srow = tid >> 2;
    int scol = (tid & 3) * (BK / 4);
    int kbeg = (KS > 1) ? blockIdx.z * (Kd / KS) : 0;
    int kend = (KS > 1) ? kbeg + Kd / KS : Kd;
    const short* Ap = A + (size_t)(bm + srow) * lda + scol;
    const short* Wp = W + (size_t)(bn + srow) * ldw + scol;
    short* Asw = &As[srow * SP + scol];
    short* Wsw = &Ws[srow * SP + scol];
    for (int k0 = kbeg; k0 < kend; k0 += BK) {
#pragma unroll
        for (int i = 0; i < BK / 32; i++) {
            *(bf16x8*)(Asw + i * 8) = *(const bf16x8*)(Ap + k0 + i * 8);
            *(bf16x8*)(Wsw + i * 8) = *(const bf16x8*)(Wp + k0 + i * 8);
        }
        __syncthreads();
#pragma unroll
        for (int ks = 0; ks < BK / 32; ks++) {
            bf16x8 af[2], bfr[2];
#pragma unroll
            for (int mi = 0; mi < 2; mi++)
                af[mi] = *(const bf16x8*)&As[(wm + mi * 16 + l15) * SP + ks * 32 + l4 * 8];
#pragma unroll
            for (int ni = 0; ni < 2; ni++)
                bfr[ni] = *(const bf16x8*)&Ws[(wn + ni * 16 + l15) * SP + ks * 32 + l4 * 8];
#pragma unroll
            for (int mi = 0; mi < 2; mi++)
#pragma unroll
                for (int ni = 0; ni < 2; ni++)
                    acc[mi][ni] = __builtin_amdgcn_mfma_f32_16x16x32_bf16(af[mi], bfr[ni], acc[mi][ni], 0, 0, 0);
        }
        __syncthreads();
    }
    if (KS > 1) {
        float* P = C + (size_t)blockIdx.z * M * N;
#pragma unroll
        for (int mi = 0; mi < 2; mi++) {
            int row0 = bm + wm + mi * 16 + l4 * 4;
#pragma unroll
            for (int ni = 0; ni < 2; ni++) {
                int col = bn + wn + ni * 16 + l15;
#pragma unroll
                for (int j = 0; j < 4; j++)
                    P[(size_t)(row0 + j) * N + col] = acc[mi][ni][j];
            }
        }
    } else {
#pragma unroll
        for (int mi = 0; mi < 2; mi++) {
            int row0 = bm + wm + mi * 16 + l4 * 4;
#pragma unroll
            for (int ni = 0; ni < 2; ni++) {
                int col = bn + wn + ni * 16 + l15;
#pragma unroll
                for (int j = 0; j < 4; j++) {
                    int row = row0 + j;
                    float v = acc[mi][ni][j];
                    if (MODE == 2) v = seluf(v + bias[col]);
                    if (MODE == 4) v = softplusf(v + bias[row]);
                    if (C)  C[(size_t)row * N + col] = v;
                    if (Cb) Cb[(size_t)row * N + col] = __float2bfloat16(v);
                }
            }
        }
    }
}

// ---------------- split-K reduce: sum KS partial slices (+ optional bias/resid) ----------------
template<int KS, int RMODE>
__global__ __launch_bounds__(256) void reduce_k(
    const float* __restrict__ P, float* __restrict__ C, bf16* __restrict__ Cb,
    const float* __restrict__ bias, const float* __restrict__ resid,
    int MN, int N)
{
    int i = (blockIdx.x * 256 + threadIdx.x) * 4;
    float4 v = *(const float4*)(P + i);
#pragma unroll
    for (int s = 1; s < KS; s++) {
        float4 u = *(const float4*)(P + (size_t)s * MN + i);
        v.x += u.x; v.y += u.y; v.z += u.z; v.w += u.w;
    }
    if (RMODE == 1) {
        float4 bz = *(const float4*)(bias + (i % N));
        float4 rx = *(const float4*)(resid + i);
        v.x += bz.x + rx.x; v.y += bz.y + rx.y;
        v.z += bz.z + rx.z; v.w += bz.w + rx.w;
    }
    if (C) *(float4*)(C + i) = v;
    if (Cb) {
        bf16* d = Cb + i;
        d[0] = __float2bfloat16(v.x); d[1] = __float2bfloat16(v.y);
        d[2] = __float2bfloat16(v.z); d[3] = __float2bfloat16(v.w);
    }
}

// ---------------- depthwise conv + SiLU, vectorized: 4 channels x 8 positions / thread ----------------
__global__ __launch_bounds__(256) void conv_silu_kernel(
    const float* __restrict__ xz, const float* __restrict__ cw,
    const float* __restrict__ cb, bf16* __restrict__ xcb)
{
    int gid = blockIdx.x * 256 + threadIdx.x;     // 131072 total
    int d4  = (gid & 255) * 4;
    int l0  = ((gid >> 8) & 127) * 8;
    int b   = (gid >> 15) & 1;
    int dir = gid >> 16;
    // weights: 48 contiguous floats = rows d4..d4+3 of cw[DI][12]
    float wv[4][12];
    {
        const float4* cwp = (const float4*)(cw + d4 * 12);
        float buf[48];
#pragma unroll
        for (int i = 0; i < 12; i++) {
            float4 t = cwp[i];
            buf[4*i] = t.x; buf[4*i+1] = t.y; buf[4*i+2] = t.z; buf[4*i+3] = t.w;
        }
#pragma unroll
        for (int dd = 0; dd < 4; dd++)
#pragma unroll
            for (int k = 0; k < 12; k++) wv[dd][k] = buf[dd * 12 + k];
    }
    float4 cb4 = *(const float4*)(cb + d4);
    // 19 taps: dir0 covers l0-11..l0+7, dir1 covers l0..l0+18
    float4 tap[19];
    int tbase = (dir == 0) ? (l0 - (K_ - 1)) : l0;
#pragma unroll
    for (int i = 0; i < 19; i++) {
        int ls = tbase + i;
        if (ls >= 0 && ls < L_)
            tap[i] = *(const float4*)(xz + ((size_t)(b * L_ + ls)) * (2 * DI_) + d4);
        else
            tap[i] = make_float4(0.f, 0.f, 0.f, 0.f);
    }
    size_t obase = (size_t)dir * BLD + ((size_t)(b * L_ + l0)) * DI_ + d4;
    if (dir == 0) {
#pragma unroll
        for (int j = 0; j < 8; j++) {
            float a0 = cb4.x, a1 = cb4.y, a2 = cb4.z, a3 = cb4.w;
#pragma unroll
            for (int k = 0; k < K_; k++) {          // weight k hits tap j+k
                float4 t = tap[j + k];
                a0 = fmaf(wv[0][k], t.x, a0); a1 = fmaf(wv[1][k], t.y, a1);
                a2 = fmaf(wv[2][k], t.z, a2); a3 = fmaf(wv[3][k], t.w, a3);
            }
            ushort4 o;
            o.x = bfbits(siluf(a0)); o.y = bfbits(siluf(a1));
            o.z = bfbits(siluf(a2)); o.w = bfbits(siluf(a3));
            *(ushort4*)(xcb + obase + (size_t)j * DI_) = o;
        }
    } else {
#pragma unroll
        for (int j = 0; j < 8; j++) {
            float a0 = cb4.x, a1 = cb4.y, a2 = cb4.z, a3 = cb4.w;
#pragma unroll
            for (int k = 0; k < K_; k++) {          // weight k hits tap j+11-k
                float4 t = tap[j + (K_ - 1) - k];
                a0 = fmaf(wv[0][k], t.x, a0); a1 = fmaf(wv[1][k], t.y, a1);
                a2 = fmaf(wv[2][k], t.z, a2); a3 = fmaf(wv[3][k], t.w, a3);
            }
            ushort4 o;
            o.x = bfbits(siluf(a0)); o.y = bfbits(siluf(a1));
            o.z = bfbits(siluf(a2)); o.w = bfbits(siluf(a3));
            *(ushort4*)(xcb + obase + (size_t)j * DI_) = o;
        }
    }
}

// ---------------- transpose bf16[2][BL][DI] -> f32[2][DI][BL] ----------------
__global__ __launch_bounds__(256) void transpose_kernel(
    const bf16* __restrict__ in, float* __restrict__ out)
{
    __shared__ float tile[32][33];
    int dir = blockIdx.z;
    int d0 = blockIdx.x * 32, l0 = blockIdx.y * 32;
    const bf16* ip = in + (size_t)dir * BLD;
    float* op = out + (size_t)dir * BLD;
    int tx = threadIdx.x & 31, ty = threadIdx.x >> 5;
#pragma unroll
    for (int r = 0; r < 4; r++) {
        int l = l0 + ty * 4 + r;
        tile[ty * 4 + r][tx] = __bfloat162float(ip[(size_t)l * DI_ + d0 + tx]);
    }
    __syncthreads();
#pragma unroll
    for (int r = 0; r < 4; r++) {
        int d = d0 + ty * 4 + r;
        op[(size_t)d * BL + l0 + tx] = tile[tx][ty * 4 + r];
    }
}

// ---------------- chunked selective scan (one dir per launch; dir1 accumulates) ----------------
__global__ __launch_bounds__(256) void scan_kernel(
    const float* __restrict__ dtT,   // [2][DI][BL]
    const float* __restrict__ xcT,   // [2][DI][BL]
    const float* __restrict__ dbl,   // [2][BL][64]
    const float* __restrict__ A_log, const float* __restrict__ Dp,
    float* __restrict__ yT,          // [DI][BL] (sum over dirs)
    int dir, int accum)
{
    __shared__ float sA[16][16];
    __shared__ float sB[16][16];
    __shared__ float sY[1024];
    int d = blockIdx.x, b = blockIdx.y;
    int tid = threadIdx.x, n = tid & 15, c = tid >> 4;
    size_t row = ((size_t)dir * DI_ + d) * BL + (size_t)b * L_;
    const float* dtp = dtT + row;
    const float* xcp = xcT + row;
    const float* dblp = dbl + ((size_t)dir * BL + (size_t)b * L_) * 64;
    float Aval = -__expf(A_log[d * N_ + n]);
    float Dd = Dp[d];
    int l0 = c * 64;
    float acum = 1.f, h = 0.f;
    for (int j = 0; j < 64; j += 4) {
        float4 dt4 = *(const float4*)(dtp + l0 + j);
        float4 xc4 = *(const float4*)(xcp + l0 + j);
#pragma unroll
        for (int q = 0; q < 4; q++) {
            float dtv = ((const float*)&dt4)[q];
            float xcv = ((const float*)&xc4)[q];
            float Bv = dblp[(l0 + j + q) * 64 + DTR_ + n];
            float a = __expf(dtv * Aval);
            acum *= a;
            h = fmaf(a, h, dtv * Bv * xcv);
        }
    }
    sA[c][n] = acum;
    sB[c][n] = h;
    __syncthreads();
    float hp = 0.f;
    for (int cc = 0; cc < c; cc++) hp = fmaf(sA[cc][n], hp, sB[cc][n]);
    h = hp;
    for (int j = 0; j < 64; j += 4) {
        float4 dt4 = *(const float4*)(dtp + l0 + j);
        float4 xc4 = *(const float4*)(xcp + l0 + j);
#pragma unroll
        for (int q = 0; q < 4; q++) {
            int l = l0 + j + q;
            float dtv = ((const float*)&dt4)[q];
            float xcv = ((const float*)&xc4)[q];
            float Bv = dblp[l * 64 + DTR_ + n];
            float Cv = dblp[l * 64 + DTR_ + N_ + n];
            float a = __expf(dtv * Aval);
            h = fmaf(a, h, dtv * Bv * xcv);
            float p = h * Cv;
            p += __shfl_xor(p, 1); p += __shfl_xor(p, 2);
            p += __shfl_xor(p, 4); p += __shfl_xor(p, 8);
            if (n == 0) sY[l] = fmaf(xcv, Dd, p);
        }
    }
    __syncthreads();
    float* yp = yT + (size_t)d * BL + (size_t)b * L_;
#pragma unroll
    for (int i = 0; i < 4; i++) {
        int idx = tid + i * 256;
        if (accum) yp[idx] += sY[idx]; else yp[idx] = sY[idx];
    }
}

// ---------------- combine + transpose: ycomb_b[bl][d] = yT[d][bl] * silu(z) ----------------
__global__ __launch_bounds__(256) void combine_kernel(
    const float* __restrict__ yT, const float* __restrict__ xz,
    bf16* __restrict__ yc)
{
    __shared__ float tile[32][33];
    int d0 = blockIdx.x * 32, bl0 = blockIdx.y * 32;
    int tx = threadIdx.x & 31, ty = threadIdx.x >> 5;
#pragma unroll
    for (int r = 0; r < 4; r++) {
        int d = d0 + ty * 4 + r;
        tile[ty * 4 + r][tx] = yT[(size_t)d * BL + bl0 + tx];
    }
    __syncthreads();
#pragma unroll
    for (int r = 0; r < 4; r++) {
        int bl = bl0 + ty * 4 + r;
        float z = xz[(size_t)bl * (2 * DI_) + DI_ + d0 + tx];
        yc[(size_t)bl * DI_ + d0 + tx] = __float2bfloat16(tile[tx][ty * 4 + r] * siluf(z));
    }
}

extern "C" void kernel_launch(void* const* d_in, const int* in_sizes, int n_in,
                              void* d_out, int out_size, void* d_ws, size_t ws_size,
                              hipStream_t stream) {
    const float* x     = (const float*)d_in[0];
    const float* mask  = (const float*)d_in[1];
    const float* n1w   = (const float*)d_in[2];
    const float* n1b   = (const float*)d_in[3];
    const float* n2w   = (const float*)d_in[4];
    const float* n2b   = (const float*)d_in[5];
    const float* ff1w  = (const float*)d_in[6];
    const float* ff1b  = (const float*)d_in[7];
    const float* ff2w  = (const float*)d_in[8];
    const float* ff2b  = (const float*)d_in[9];
    const float* inpw  = (const float*)d_in[10];
    const float* convw = (const float*)d_in[11];
    const float* convb = (const float*)d_in[12];
    const float* xpw   = (const float*)d_in[13];
    const float* dtpw  = (const float*)d_in[14];
    const float *A_log, *Dp, *outpw, *dtpb;
    if (in_sizes[15] == DI_ * N_) {
        A_log = (const float*)d_in[15]; Dp = (const float*)d_in[16];
        outpw = (const float*)d_in[17]; dtpb = (const float*)d_in[18];
    } else {
        dtpb = (const float*)d_in[15]; A_log = (const float*)d_in[16];
        Dp = (const float*)d_in[17]; outpw = (const float*)d_in[18];
    }

    float* ws = (float*)d_ws;
    bf16*  wb      = (bf16*)ws;                         // 1884160 fu
    float* xz      = ws + 1884160;                      // 4194304 fu (also P9/P12 partials)
    bf16*  xn_b    = (bf16*)(ws + 6078464);             // 524288 fu (also mon_b)
    bf16*  xc_b    = (bf16*)(ws + 6602752);             // 2097152 fu (also h_b)
    float* xcT     = ws + 8699904;                      // 4194304 fu
    float* dblb    = ws + 12894208;                     // 262144 fu
    bf16*  dbl_b   = (bf16*)(ws + 13156352);            // 131072 fu
    float* dtT     = ws + 13287424;                     // 4194304 fu (also P5 partials, moraw)
    float* yT      = ws + 17481728;                     // 2097152 fu
    bf16*  ycomb_b = (bf16*)(ws + 19578880);            // 524288 fu

    bf16* inpw_b = wb;
    bf16* xpw_b  = wb + 1048576;
    bf16* dtpw_b = wb + 1114112;
    bf16* outpw_b= wb + 1146880;
    bf16* ff1w_b = wb + 1671168;
    bf16* ff2w_b = wb + 2719744;
    bf16* mon_b  = xn_b;
    bf16* h_b    = xc_b;
    float* moraw = dtT;
    float* P5    = dtT;
    float* P9    = xz;
    float* P12   = xz;

    // 0. cast weights to bf16
    cast_w<<<dim3(3680), 256, 0, stream>>>(inpw, xpw, dtpw, outpw, ff1w, ff2w, wb);
    // 1. xn = LN(x) -> bf16
    ln_kernel<<<dim3(BL / 4), 256, 0, stream>>>(x, n1w, n1b, nullptr, xn_b);
    // 2. xz = xn @ in_proj_w^T (2048x2048x512), grid 1024
    mgemm_k<0, 64, 1><<<dim3(32, 32), 256, 0, stream>>>(
        (const short*)xn_b, DM_, (const short*)inpw_b, DM_, xz, nullptr,
        nullptr, BL, 2 * DI_, DM_);
    // 3. conv + silu -> bf16 (vectorized 4ch x 8pos)
    conv_silu_kernel<<<dim3(512), 256, 0, stream>>>(xz, convw, convb, xc_b);
    // 4. xcT = f32 transpose(xc_b)
    transpose_kernel<<<dim3(DI_ / 32, BL / 32, 2), 256, 0, stream>>>(xc_b, xcT);
    // 5. dbl = xc @ x_proj_w^T (4096x64x1024), split-K 8, grid 512
    mgemm_k<0, 64, 8><<<dim3(1, 64, 8), 256, 0, stream>>>(
        (const short*)xc_b, DI_, (const short*)xpw_b, DI_, P5, nullptr,
        nullptr, 2 * BL, 64, DI_);
    reduce_k<8, 0><<<dim3(256), 256, 0, stream>>>(P5, dblb, dbl_b, nullptr, nullptr,
                                                  2 * BL * 64, 64);
    // 6. dtT = softplus(dt_proj_w @ dt_r^T + b[m]) -> [DI][BL] per dir, grid 512 each
    for (int dir = 0; dir < 2; dir++)
        mgemm_k<4, 32, 1><<<dim3(32, 16), 256, 0, stream>>>(
            (const short*)dtpw_b, DTR_, (const short*)(dbl_b + (size_t)dir * BL * 64), 64,
            dtT + (size_t)dir * (size_t)DI_ * BL, nullptr, dtpb, DI_, BL, DTR_);
    // 7. chunked scan: dir0 writes, dir1 accumulates
    scan_kernel<<<dim3(DI_, B_), 256, 0, stream>>>(dtT, xcT, dblb, A_log, Dp, yT, 0, 0);
    scan_kernel<<<dim3(DI_, B_), 256, 0, stream>>>(dtT, xcT, dblb, A_log, Dp, yT, 1, 1);
    // 8. ycomb_b = yT^T * silu(z) -> bf16
    combine_kernel<<<dim3(DI_ / 32, BL / 32), 256, 0, stream>>>(yT, xz, ycomb_b);
    // 9. mo_raw = ycomb @ out_proj_w^T (2048x512x1024), split-K 2, grid 512
    mgemm_k<0, 64, 2><<<dim3(8, 32, 2), 256, 0, stream>>>(
        (const short*)ycomb_b, DI_, (const short*)outpw_b, DI_, P9, nullptr,
        nullptr, BL, DM_, DI_);
    reduce_k<2, 0><<<dim3(1024), 256, 0, stream>>>(P9, moraw, nullptr, nullptr, nullptr,
                                                   BL * DM_, DM_);
    // 10. mo_n = LN(mo_raw * mask) -> bf16
    ln_kernel<<<dim3(BL / 4), 256, 0, stream>>>(moraw, n2w, n2b, mask, mon_b);
    // 11. h = selu(mo_n @ ff1_w^T + b) -> bf16 (2048x2048x512), grid 1024
    mgemm_k<2, 64, 1><<<dim3(32, 32), 256, 0, stream>>>(
        (const short*)mon_b, DM_, (const short*)ff1w_b, DM_, nullptr, h_b,
        ff1b, BL, 4 * DM_, DM_);
    // 12. out = h @ ff2_w^T (2048x512x2048), split-K 2, grid 512; reduce adds bias + x
    mgemm_k<0, 64, 2><<<dim3(8, 32, 2), 256, 0, stream>>>(
        (const short*)h_b, 4 * DM_, (const short*)ff2w_b, 4 * DM_, P12, nullptr,
        nullptr, BL, DM_, 4 * DM_);
    reduce_k<2, 1><<<dim3(1024), 256, 0, stream>>>(P12, (float*)d_out, nullptr, ff2b, x,
                                                   BL * DM_, DM_);
}

// Round 7
// 210.564 us; speedup vs baseline: 4.3733x; 1.1269x over previous
//
#include <hip/hip_runtime.h>
#include <hip/hip_bf16.h>

typedef __hip_bfloat16 bf16;

#define B_   2
#define L_   1024
#define DM_  512
#define DI_  1024
#define N_   16
#define K_   12
#define DTR_ 32

static constexpr int BLD  = B_ * L_ * DI_;   // 2097152
static constexpr int BL   = B_ * L_;         // 2048

using bf16x8 = __attribute__((ext_vector_type(8))) short;
using f32x4  = __attribute__((ext_vector_type(4))) float;

__device__ __forceinline__ float siluf(float x) { return x / (1.f + __expf(-x)); }
__device__ __forceinline__ float softplusf(float x) {
    return fmaxf(x, 0.f) + log1pf(expf(-fabsf(x)));
}
__device__ __forceinline__ float seluf(float x) {
    const float lam = 1.0507009873554805f, alp = 1.6732632423543772f;
    return x > 0.f ? lam * x : lam * alp * (expf(x) - 1.f);
}
__device__ __forceinline__ ushort bfbits(float x) {
    bf16 v = __float2bfloat16(x);
    return *(ushort*)&v;
}

// ---------------- weight cast f32 -> bf16 (6 segments, vec4) ----------------
__global__ __launch_bounds__(256) void cast_w(
    const float* __restrict__ s0, const float* __restrict__ s1, const float* __restrict__ s2,
    const float* __restrict__ s3, const float* __restrict__ s4, const float* __restrict__ s5,
    bf16* __restrict__ dst)
{
    int i = blockIdx.x * 256 + threadIdx.x;   // total 942080 vec4
    const float* src; int off;
    if (i < 262144)      { src = s0; off = i; }
    else if (i < 278528) { src = s1; off = i - 262144; }
    else if (i < 286720) { src = s2; off = i - 278528; }
    else if (i < 417792) { src = s3; off = i - 286720; }
    else if (i < 679936) { src = s4; off = i - 417792; }
    else                 { src = s5; off = i - 679936; }
    float4 v = ((const float4*)src)[off];
    bf16* d = dst + (size_t)i * 4;
    d[0] = __float2bfloat16(v.x); d[1] = __float2bfloat16(v.y);
    d[2] = __float2bfloat16(v.z); d[3] = __float2bfloat16(v.w);
}

// ---------------- LayerNorm: one wave per row of 512, bf16 out ----------------
__global__ __launch_bounds__(256) void ln_kernel(
    const float* __restrict__ x, const float* __restrict__ w, const float* __restrict__ b,
    const float* __restrict__ mask, bf16* __restrict__ y)
{
    int row  = blockIdx.x * 4 + (threadIdx.x >> 6);
    int lane = threadIdx.x & 63;
    const float* xr = x + (size_t)row * DM_;
    float mval = mask ? mask[row] : 1.0f;
    float v[8];
    float s = 0.f, ss = 0.f;
#pragma unroll
    for (int i = 0; i < 8; i++) {
        v[i] = xr[lane + i * 64] * mval;
        s += v[i]; ss += v[i] * v[i];
    }
#pragma unroll
    for (int o = 32; o >= 1; o >>= 1) { s += __shfl_xor(s, o); ss += __shfl_xor(ss, o); }
    float mean = s * (1.f / DM_);
    float var  = ss * (1.f / DM_) - mean * mean;
    float r    = rsqrtf(var + 1e-5f);
    bf16* yr = y + (size_t)row * DM_;
#pragma unroll
    for (int i = 0; i < 8; i++) {
        int c = lane + i * 64;
        yr[c] = __float2bfloat16((v[i] - mean) * r * w[c] + b[c]);
    }
}

// ---------------- MFMA GEMM: C(M,N) = A(M,K) @ W(N,K)^T  (bf16 in, fp32 acc) ----------------
// KS>1: write fp32 partials. KS==1 MODE: 0 plain  1 bias[n]+softplus  2 bias[n]+selu
template<int MODE, int BK, int KS>
__global__ __launch_bounds__(256) void mgemm_k(
    const short* __restrict__ A, int lda,
    const short* __restrict__ W, int ldw,
    float* __restrict__ C, bf16* __restrict__ Cb,
    const float* __restrict__ bias,
    int M, int N, int Kd)
{
    constexpr int SP = BK + 8;                // padded LDS row stride (bf16 elems)
    __shared__ short As[64 * SP];
    __shared__ short Ws[64 * SP];
    int bm = blockIdx.y * 64, bn = blockIdx.x * 64;
    int tid = threadIdx.x;
    int lane = tid & 63, w = tid >> 6;
    int wm = (w >> 1) * 32, wn = (w & 1) * 32;
    int l15 = lane & 15, l4 = lane >> 4;
    f32x4 acc[2][2] = {};
    int srow = tid >> 2;
    int scol = (tid & 3) * (BK / 4);
    int kbeg = (KS > 1) ? blockIdx.z * (Kd / KS) : 0;
    int kend = (KS > 1) ? kbeg + Kd / KS : Kd;
    const short* Ap = A + (size_t)(bm + srow) * lda + scol;
    const short* Wp = W + (size_t)(bn + srow) * ldw + scol;
    short* Asw = &As[srow * SP + scol];
    short* Wsw = &Ws[srow * SP + scol];
    for (int k0 = kbeg; k0 < kend; k0 += BK) {
#pragma unroll
        for (int i = 0; i < BK / 32; i++) {
            *(bf16x8*)(Asw + i * 8) = *(const bf16x8*)(Ap + k0 + i * 8);
            *(bf16x8*)(Wsw + i * 8) = *(const bf16x8*)(Wp + k0 + i * 8);
        }
        __syncthreads();
#pragma unroll
        for (int ks = 0; ks < BK / 32; ks++) {
            bf16x8 af[2], bfr[2];
#pragma unroll
            for (int mi = 0; mi < 2; mi++)
                af[mi] = *(const bf16x8*)&As[(wm + mi * 16 + l15) * SP + ks * 32 + l4 * 8];
#pragma unroll
            for (int ni = 0; ni < 2; ni++)
                bfr[ni] = *(const bf16x8*)&Ws[(wn + ni * 16 + l15) * SP + ks * 32 + l4 * 8];
#pragma unroll
            for (int mi = 0; mi < 2; mi++)
#pragma unroll
                for (int ni = 0; ni < 2; ni++)
                    acc[mi][ni] = __builtin_amdgcn_mfma_f32_16x16x32_bf16(af[mi], bfr[ni], acc[mi][ni], 0, 0, 0);
        }
        __syncthreads();
    }
    if (KS > 1) {
        float* P = C + (size_t)blockIdx.z * M * N;
#pragma unroll
        for (int mi = 0; mi < 2; mi++) {
            int row0 = bm + wm + mi * 16 + l4 * 4;
#pragma unroll
            for (int ni = 0; ni < 2; ni++) {
                int col = bn + wn + ni * 16 + l15;
#pragma unroll
                for (int j = 0; j < 4; j++)
                    P[(size_t)(row0 + j) * N + col] = acc[mi][ni][j];
            }
        }
    } else {
#pragma unroll
        for (int mi = 0; mi < 2; mi++) {
            int row0 = bm + wm + mi * 16 + l4 * 4;
#pragma unroll
            for (int ni = 0; ni < 2; ni++) {
                int col = bn + wn + ni * 16 + l15;
#pragma unroll
                for (int j = 0; j < 4; j++) {
                    int row = row0 + j;
                    float v = acc[mi][ni][j];
                    if (MODE == 1) v = softplusf(v + bias[col]);
                    if (MODE == 2) v = seluf(v + bias[col]);
                    if (C)  C[(size_t)row * N + col] = v;
                    if (Cb) Cb[(size_t)row * N + col] = __float2bfloat16(v);
                }
            }
        }
    }
}

// ---------------- split-K reduce: sum KS partial slices (+ optional bias/resid) ----------------
template<int KS, int RMODE>
__global__ __launch_bounds__(256) void reduce_k(
    const float* __restrict__ P, float* __restrict__ C, bf16* __restrict__ Cb,
    const float* __restrict__ bias, const float* __restrict__ resid,
    int MN, int N)
{
    int i = (blockIdx.x * 256 + threadIdx.x) * 4;
    float4 v = *(const float4*)(P + i);
#pragma unroll
    for (int s = 1; s < KS; s++) {
        float4 u = *(const float4*)(P + (size_t)s * MN + i);
        v.x += u.x; v.y += u.y; v.z += u.z; v.w += u.w;
    }
    if (RMODE == 1) {
        float4 bz = *(const float4*)(bias + (i % N));
        float4 rx = *(const float4*)(resid + i);
        v.x += bz.x + rx.x; v.y += bz.y + rx.y;
        v.z += bz.z + rx.z; v.w += bz.w + rx.w;
    }
    if (C) *(float4*)(C + i) = v;
    if (Cb) {
        bf16* d = Cb + i;
        d[0] = __float2bfloat16(v.x); d[1] = __float2bfloat16(v.y);
        d[2] = __float2bfloat16(v.z); d[3] = __float2bfloat16(v.w);
    }
}

// ---------------- depthwise conv + SiLU, vectorized: 4 channels x 8 positions / thread ----------------
__global__ __launch_bounds__(256) void conv_silu_kernel(
    const float* __restrict__ xz, const float* __restrict__ cw,
    const float* __restrict__ cb, bf16* __restrict__ xcb)
{
    int gid = blockIdx.x * 256 + threadIdx.x;     // 131072 total
    int d4  = (gid & 255) * 4;
    int l0  = ((gid >> 8) & 127) * 8;
    int b   = (gid >> 15) & 1;
    int dir = gid >> 16;
    float wv[4][12];
    {
        const float4* cwp = (const float4*)(cw + d4 * 12);
        float buf[48];
#pragma unroll
        for (int i = 0; i < 12; i++) {
            float4 t = cwp[i];
            buf[4*i] = t.x; buf[4*i+1] = t.y; buf[4*i+2] = t.z; buf[4*i+3] = t.w;
        }
#pragma unroll
        for (int dd = 0; dd < 4; dd++)
#pragma unroll
            for (int k = 0; k < 12; k++) wv[dd][k] = buf[dd * 12 + k];
    }
    float4 cb4 = *(const float4*)(cb + d4);
    float4 tap[19];
    int tbase = (dir == 0) ? (l0 - (K_ - 1)) : l0;
#pragma unroll
    for (int i = 0; i < 19; i++) {
        int ls = tbase + i;
        if (ls >= 0 && ls < L_)
            tap[i] = *(const float4*)(xz + ((size_t)(b * L_ + ls)) * (2 * DI_) + d4);
        else
            tap[i] = make_float4(0.f, 0.f, 0.f, 0.f);
    }
    size_t obase = (size_t)dir * BLD + ((size_t)(b * L_ + l0)) * DI_ + d4;
    if (dir == 0) {
#pragma unroll
        for (int j = 0; j < 8; j++) {
            float a0 = cb4.x, a1 = cb4.y, a2 = cb4.z, a3 = cb4.w;
#pragma unroll
            for (int k = 0; k < K_; k++) {
                float4 t = tap[j + k];
                a0 = fmaf(wv[0][k], t.x, a0); a1 = fmaf(wv[1][k], t.y, a1);
                a2 = fmaf(wv[2][k], t.z, a2); a3 = fmaf(wv[3][k], t.w, a3);
            }
            ushort4 o;
            o.x = bfbits(siluf(a0)); o.y = bfbits(siluf(a1));
            o.z = bfbits(siluf(a2)); o.w = bfbits(siluf(a3));
            *(ushort4*)(xcb + obase + (size_t)j * DI_) = o;
        }
    } else {
#pragma unroll
        for (int j = 0; j < 8; j++) {
            float a0 = cb4.x, a1 = cb4.y, a2 = cb4.z, a3 = cb4.w;
#pragma unroll
            for (int k = 0; k < K_; k++) {
                float4 t = tap[j + (K_ - 1) - k];
                a0 = fmaf(wv[0][k], t.x, a0); a1 = fmaf(wv[1][k], t.y, a1);
                a2 = fmaf(wv[2][k], t.z, a2); a3 = fmaf(wv[3][k], t.w, a3);
            }
            ushort4 o;
            o.x = bfbits(siluf(a0)); o.y = bfbits(siluf(a1));
            o.z = bfbits(siluf(a2)); o.w = bfbits(siluf(a3));
            *(ushort4*)(xcb + obase + (size_t)j * DI_) = o;
        }
    }
}

// ---------------- chunked selective scan, 4 n-states per lane ----------------
// block 256 thr = 16 chunks x 4 ngrp x 4 dloc; grid (DI/4, B, 2 dirs)
__global__ __launch_bounds__(256) void scan_kernel(
    const float* __restrict__ dt,    // [2][BL][DI] f32
    const bf16*  __restrict__ xc,    // [2][BL][DI] bf16
    const float* __restrict__ dbl,   // [2][BL][64] f32
    const float* __restrict__ A_log, const float* __restrict__ Dp,
    float* __restrict__ y2)          // [2][DI][BL] f32
{
    __shared__ float sA[16][4][17];
    __shared__ float sB[16][4][17];
    __shared__ float sY[4][1028];
    int dgrp = blockIdx.x, b = blockIdx.y, dir = blockIdx.z;
    int tid = threadIdx.x;
    int dloc = tid & 3, ng = (tid >> 2) & 3, c = tid >> 4;
    int d = dgrp * 4 + dloc;
    size_t ibase = ((size_t)dir * BL + (size_t)b * L_) * DI_ + d;
    const float* dtp = dt + ibase;
    const bf16*  xcp = xc + ibase;
    const float* dblp = dbl + ((size_t)dir * BL + (size_t)b * L_) * 64;
    int nb = ng * 4;
    float A0 = -__expf(A_log[d * N_ + nb + 0]);
    float A1 = -__expf(A_log[d * N_ + nb + 1]);
    float A2 = -__expf(A_log[d * N_ + nb + 2]);
    float A3 = -__expf(A_log[d * N_ + nb + 3]);
    float Dd = Dp[d];
    int l0 = c * 64;
    // pass 1: local scan -> chunk summaries (per n)
    float ac0=1.f, ac1=1.f, ac2=1.f, ac3=1.f;
    float h0=0.f, h1=0.f, h2=0.f, h3=0.f;
    for (int j = 0; j < 64; j++) {
        int l = l0 + j;
        float dtv = dtp[(size_t)l * DI_];
        float xcv = __bfloat162float(xcp[(size_t)l * DI_]);
        float4 B4 = *(const float4*)(dblp + (size_t)l * 64 + DTR_ + nb);
        float dx = dtv * xcv;
        float a0 = __expf(dtv * A0), a1 = __expf(dtv * A1),
              a2 = __expf(dtv * A2), a3 = __expf(dtv * A3);
        ac0 *= a0; ac1 *= a1; ac2 *= a2; ac3 *= a3;
        h0 = fmaf(a0, h0, dx * B4.x); h1 = fmaf(a1, h1, dx * B4.y);
        h2 = fmaf(a2, h2, dx * B4.z); h3 = fmaf(a3, h3, dx * B4.w);
    }
    sA[c][dloc][nb+0]=ac0; sA[c][dloc][nb+1]=ac1; sA[c][dloc][nb+2]=ac2; sA[c][dloc][nb+3]=ac3;
    sB[c][dloc][nb+0]=h0;  sB[c][dloc][nb+1]=h1;  sB[c][dloc][nb+2]=h2;  sB[c][dloc][nb+3]=h3;
    __syncthreads();
    // exclusive cross-chunk prefix (<=15 steps)
    float p0=0.f, p1=0.f, p2=0.f, p3=0.f;
    for (int cc = 0; cc < c; cc++) {
        p0 = fmaf(sA[cc][dloc][nb+0], p0, sB[cc][dloc][nb+0]);
        p1 = fmaf(sA[cc][dloc][nb+1], p1, sB[cc][dloc][nb+1]);
        p2 = fmaf(sA[cc][dloc][nb+2], p2, sB[cc][dloc][nb+2]);
        p3 = fmaf(sA[cc][dloc][nb+3], p3, sB[cc][dloc][nb+3]);
    }
    h0 = p0; h1 = p1; h2 = p2; h3 = p3;
    // pass 2: rescan + reduce over n (in-reg 4 + 2 shfl over ngrp)
    for (int j = 0; j < 64; j++) {
        int l = l0 + j;
        float dtv = dtp[(size_t)l * DI_];
        float xcv = __bfloat162float(xcp[(size_t)l * DI_]);
        float4 B4 = *(const float4*)(dblp + (size_t)l * 64 + DTR_ + nb);
        float4 C4 = *(const float4*)(dblp + (size_t)l * 64 + DTR_ + N_ + nb);
        float dx = dtv * xcv;
        float a0 = __expf(dtv * A0), a1 = __expf(dtv * A1),
              a2 = __expf(dtv * A2), a3 = __expf(dtv * A3);
        h0 = fmaf(a0, h0, dx * B4.x); h1 = fmaf(a1, h1, dx * B4.y);
        h2 = fmaf(a2, h2, dx * B4.z); h3 = fmaf(a3, h3, dx * B4.w);
        float p = h0 * C4.x;
        p = fmaf(h1, C4.y, p); p = fmaf(h2, C4.z, p); p = fmaf(h3, C4.w, p);
        p += __shfl_xor(p, 4); p += __shfl_xor(p, 8);
        if (ng == 0) sY[dloc][l] = fmaf(xcv, Dd, p);
    }
    __syncthreads();
    // coalesced write: 4 d-rows x 1024 l
    float* yp = y2 + ((size_t)dir * DI_ + (size_t)dgrp * 4) * BL + (size_t)b * L_;
    int lw = tid * 4;
#pragma unroll
    for (int dd = 0; dd < 4; dd++)
        *(float4*)(yp + (size_t)dd * BL + lw) = *(float4*)&sY[dd][lw];
}

// ---------------- combine + transpose: ycomb_b[bl][d] = (y2_f+y2_b)[d][bl] * silu(z) ----------------
__global__ __launch_bounds__(256) void combine_kernel(
    const float* __restrict__ y2, const float* __restrict__ xz,
    bf16* __restrict__ yc)
{
    __shared__ float tile[32][33];
    int d0 = blockIdx.x * 32, bl0 = blockIdx.y * 32;
    int tx = threadIdx.x & 31, ty = threadIdx.x >> 5;
#pragma unroll
    for (int r = 0; r < 4; r++) {
        int d = d0 + ty * 4 + r;
        tile[ty * 4 + r][tx] = y2[(size_t)d * BL + bl0 + tx]
                             + y2[(size_t)(DI_ + d) * BL + bl0 + tx];
    }
    __syncthreads();
#pragma unroll
    for (int r = 0; r < 4; r++) {
        int bl = bl0 + ty * 4 + r;
        float z = xz[(size_t)bl * (2 * DI_) + DI_ + d0 + tx];
        yc[(size_t)bl * DI_ + d0 + tx] = __float2bfloat16(tile[tx][ty * 4 + r] * siluf(z));
    }
}

extern "C" void kernel_launch(void* const* d_in, const int* in_sizes, int n_in,
                              void* d_out, int out_size, void* d_ws, size_t ws_size,
                              hipStream_t stream) {
    const float* x     = (const float*)d_in[0];
    const float* mask  = (const float*)d_in[1];
    const float* n1w   = (const float*)d_in[2];
    const float* n1b   = (const float*)d_in[3];
    const float* n2w   = (const float*)d_in[4];
    const float* n2b   = (const float*)d_in[5];
    const float* ff1w  = (const float*)d_in[6];
    const float* ff1b  = (const float*)d_in[7];
    const float* ff2w  = (const float*)d_in[8];
    const float* ff2b  = (const float*)d_in[9];
    const float* inpw  = (const float*)d_in[10];
    const float* convw = (const float*)d_in[11];
    const float* convb = (const float*)d_in[12];
    const float* xpw   = (const float*)d_in[13];
    const float* dtpw  = (const float*)d_in[14];
    const float *A_log, *Dp, *outpw, *dtpb;
    if (in_sizes[15] == DI_ * N_) {
        A_log = (const float*)d_in[15]; Dp = (const float*)d_in[16];
        outpw = (const float*)d_in[17]; dtpb = (const float*)d_in[18];
    } else {
        dtpb = (const float*)d_in[15]; A_log = (const float*)d_in[16];
        Dp = (const float*)d_in[17]; outpw = (const float*)d_in[18];
    }

    float* ws = (float*)d_ws;
    bf16*  wb      = (bf16*)ws;                         // 1884160 fu
    float* xz      = ws + 1884160;                      // 4194304 fu (also P9/P12)
    bf16*  xn_b    = (bf16*)(ws + 6078464);             // 524288 fu (also mon_b)
    bf16*  xc_b    = (bf16*)(ws + 6602752);             // 2097152 fu (also h_b)
    float* y2      = ws + 8699904;                      // 4194304 fu  [2][DI][BL]
    float* dblb    = ws + 12894208;                     // 262144 fu
    bf16*  dbl_b   = (bf16*)(ws + 13156352);            // 131072 fu
    float* dtf     = ws + 13287424;                     // 4194304 fu (also P5, moraw)
    bf16*  ycomb_b = (bf16*)(ws + 19578880);            // 524288 fu

    bf16* inpw_b = wb;
    bf16* xpw_b  = wb + 1048576;
    bf16* dtpw_b = wb + 1114112;
    bf16* outpw_b= wb + 1146880;
    bf16* ff1w_b = wb + 1671168;
    bf16* ff2w_b = wb + 2719744;
    bf16* mon_b  = xn_b;
    bf16* h_b    = xc_b;
    float* moraw = dtf;
    float* P5    = dtf;
    float* P9    = xz;
    float* P12   = xz;

    // 0. cast weights to bf16
    cast_w<<<dim3(3680), 256, 0, stream>>>(inpw, xpw, dtpw, outpw, ff1w, ff2w, wb);
    // 1. xn = LN(x) -> bf16
    ln_kernel<<<dim3(BL / 4), 256, 0, stream>>>(x, n1w, n1b, nullptr, xn_b);
    // 2. xz = xn @ in_proj_w^T (2048x2048x512), grid 1024
    mgemm_k<0, 64, 1><<<dim3(32, 32), 256, 0, stream>>>(
        (const short*)xn_b, DM_, (const short*)inpw_b, DM_, xz, nullptr,
        nullptr, BL, 2 * DI_, DM_);
    // 3. conv + silu -> bf16 (vectorized 4ch x 8pos)
    conv_silu_kernel<<<dim3(512), 256, 0, stream>>>(xz, convw, convb, xc_b);
    // 4. dbl = xc @ x_proj_w^T (4096x64x1024), split-K 8, grid 512
    mgemm_k<0, 64, 8><<<dim3(1, 64, 8), 256, 0, stream>>>(
        (const short*)xc_b, DI_, (const short*)xpw_b, DI_, P5, nullptr,
        nullptr, 2 * BL, 64, DI_);
    reduce_k<8, 0><<<dim3(256), 256, 0, stream>>>(P5, dblb, dbl_b, nullptr, nullptr,
                                                  2 * BL * 64, 64);
    // 5. dt = softplus(dt_r @ dt_proj_w^T + b) -> f32 [2][BL][DI], grid 512 each
    for (int dir = 0; dir < 2; dir++)
        mgemm_k<1, 32, 1><<<dim3(16, 32), 256, 0, stream>>>(
            (const short*)(dbl_b + (size_t)dir * BL * 64), 64, (const short*)dtpw_b, DTR_,
            dtf + (size_t)dir * BLD, nullptr, dtpb, BL, DI_, DTR_);
    // 6. chunked scan (both dirs, one launch) -> y2[2][DI][BL]
    scan_kernel<<<dim3(DI_ / 4, B_, 2), 256, 0, stream>>>(dtf, xc_b, dblb, A_log, Dp, y2);
    // 7. ycomb_b = (y2_f + y2_b)^T * silu(z) -> bf16
    combine_kernel<<<dim3(DI_ / 32, BL / 32), 256, 0, stream>>>(y2, xz, ycomb_b);
    // 8. mo_raw = ycomb @ out_proj_w^T (2048x512x1024), split-K 2, grid 512
    mgemm_k<0, 64, 2><<<dim3(8, 32, 2), 256, 0, stream>>>(
        (const short*)ycomb_b, DI_, (const short*)outpw_b, DI_, P9, nullptr,
        nullptr, BL, DM_, DI_);
    reduce_k<2, 0><<<dim3(1024), 256, 0, stream>>>(P9, moraw, nullptr, nullptr, nullptr,
                                                   BL * DM_, DM_);
    // 9. mo_n = LN(mo_raw * mask) -> bf16
    ln_kernel<<<dim3(BL / 4), 256, 0, stream>>>(moraw, n2w, n2b, mask, mon_b);
    // 10. h = selu(mo_n @ ff1_w^T + b) -> bf16 (2048x2048x512), grid 1024
    mgemm_k<2, 64, 1><<<dim3(32, 32), 256, 0, stream>>>(
        (const short*)mon_b, DM_, (const short*)ff1w_b, DM_, nullptr, h_b,
        ff1b, BL, 4 * DM_, DM_);
    // 11. out = h @ ff2_w^T (2048x512x2048), split-K 2, grid 512; reduce adds bias + x
    mgemm_k<0, 64, 2><<<dim3(8, 32, 2), 256, 0, stream>>>(
        (const short*)h_b, 4 * DM_, (const short*)ff2w_b, 4 * DM_, P12, nullptr,
        nullptr, BL, DM_, 4 * DM_);
    reduce_k<2, 1><<<dim3(1024), 256, 0, stream>>>(P12, (float*)d_out, nullptr, ff2b, x,
                                                   BL * DM_, DM_);
}

// Round 8
// 207.225 us; speedup vs baseline: 4.4437x; 1.0161x over previous
//
#include <hip/hip_runtime.h>
#include <hip/hip_bf16.h>

typedef __hip_bfloat16 bf16;

#define B_   2
#define L_   1024
#define DM_  512
#define DI_  1024
#define N_   16
#define K_   12
#define DTR_ 32

static constexpr int BLD  = B_ * L_ * DI_;   // 2097152
static constexpr int BL   = B_ * L_;         // 2048

using bf16x8 = __attribute__((ext_vector_type(8))) short;
using f32x4  = __attribute__((ext_vector_type(4))) float;

__device__ __forceinline__ float siluf(float x) { return x / (1.f + __expf(-x)); }
__device__ __forceinline__ float softplusf(float x) {
    return fmaxf(x, 0.f) + log1pf(expf(-fabsf(x)));
}
__device__ __forceinline__ float seluf(float x) {
    const float lam = 1.0507009873554805f, alp = 1.6732632423543772f;
    return x > 0.f ? lam * x : lam * alp * (expf(x) - 1.f);
}
__device__ __forceinline__ ushort bfbits(float x) {
    bf16 v = __float2bfloat16(x);
    return *(ushort*)&v;
}
__device__ __forceinline__ float bf2f(ushort u) {
    return __uint_as_float(((unsigned)u) << 16);
}

// ---------------- weight cast f32 -> bf16 (6 segments, vec4) ----------------
__global__ __launch_bounds__(256) void cast_w(
    const float* __restrict__ s0, const float* __restrict__ s1, const float* __restrict__ s2,
    const float* __restrict__ s3, const float* __restrict__ s4, const float* __restrict__ s5,
    bf16* __restrict__ dst)
{
    int i = blockIdx.x * 256 + threadIdx.x;   // total 942080 vec4
    const float* src; int off;
    if (i < 262144)      { src = s0; off = i; }
    else if (i < 278528) { src = s1; off = i - 262144; }
    else if (i < 286720) { src = s2; off = i - 278528; }
    else if (i < 417792) { src = s3; off = i - 286720; }
    else if (i < 679936) { src = s4; off = i - 417792; }
    else                 { src = s5; off = i - 679936; }
    float4 v = ((const float4*)src)[off];
    bf16* d = dst + (size_t)i * 4;
    d[0] = __float2bfloat16(v.x); d[1] = __float2bfloat16(v.y);
    d[2] = __float2bfloat16(v.z); d[3] = __float2bfloat16(v.w);
}

// ---------------- LayerNorm: one wave per row of 512, bf16 out ----------------
__global__ __launch_bounds__(256) void ln_kernel(
    const float* __restrict__ x, const float* __restrict__ w, const float* __restrict__ b,
    const float* __restrict__ mask, bf16* __restrict__ y)
{
    int row  = blockIdx.x * 4 + (threadIdx.x >> 6);
    int lane = threadIdx.x & 63;
    const float* xr = x + (size_t)row * DM_;
    float mval = mask ? mask[row] : 1.0f;
    float v[8];
    float s = 0.f, ss = 0.f;
#pragma unroll
    for (int i = 0; i < 8; i++) {
        v[i] = xr[lane + i * 64] * mval;
        s += v[i]; ss += v[i] * v[i];
    }
#pragma unroll
    for (int o = 32; o >= 1; o >>= 1) { s += __shfl_xor(s, o); ss += __shfl_xor(ss, o); }
    float mean = s * (1.f / DM_);
    float var  = ss * (1.f / DM_) - mean * mean;
    float r    = rsqrtf(var + 1e-5f);
    bf16* yr = y + (size_t)row * DM_;
#pragma unroll
    for (int i = 0; i < 8; i++) {
        int c = lane + i * 64;
        yr[c] = __float2bfloat16((v[i] - mean) * r * w[c] + b[c]);
    }
}

// ---------------- MFMA GEMM: C(M,N) = A(M,K) @ W(N,K)^T  (bf16 in, fp32 acc) ----------------
// KS>1: write fp32 partials. KS==1 MODE: 0 plain  1 bias[n]+softplus  2 bias[n]+selu  4 bias[m]+softplus
template<int MODE, int BK, int KS>
__global__ __launch_bounds__(256) void mgemm_k(
    const short* __restrict__ A, int lda,
    const short* __restrict__ W, int ldw,
    float* __restrict__ C, bf16* __restrict__ Cb,
    const float* __restrict__ bias,
    int M, int N, int Kd)
{
    constexpr int SP = BK + 8;                // padded LDS row stride (bf16 elems)
    __shared__ short As[64 * SP];
    __shared__ short Ws[64 * SP];
    int bm = blockIdx.y * 64, bn = blockIdx.x * 64;
    int tid = threadIdx.x;
    int lane = tid & 63, w = tid >> 6;
    int wm = (w >> 1) * 32, wn = (w & 1) * 32;
    int l15 = lane & 15, l4 = lane >> 4;
    f32x4 acc[2][2] = {};
    int srow = tid >> 2;
    int scol = (tid & 3) * (BK / 4);
    int kbeg = (KS > 1) ? blockIdx.z * (Kd / KS) : 0;
    int kend = (KS > 1) ? kbeg + Kd / KS : Kd;
    const short* Ap = A + (size_t)(bm + srow) * lda + scol;
    const short* Wp = W + (size_t)(bn + srow) * ldw + scol;
    short* Asw = &As[srow * SP + scol];
    short* Wsw = &Ws[srow * SP + scol];
    for (int k0 = kbeg; k0 < kend; k0 += BK) {
#pragma unroll
        for (int i = 0; i < BK / 32; i++) {
            *(bf16x8*)(Asw + i * 8) = *(const bf16x8*)(Ap + k0 + i * 8);
            *(bf16x8*)(Wsw + i * 8) = *(const bf16x8*)(Wp + k0 + i * 8);
        }
        __syncthreads();
#pragma unroll
        for (int ks = 0; ks < BK / 32; ks++) {
            bf16x8 af[2], bfr[2];
#pragma unroll
            for (int mi = 0; mi < 2; mi++)
                af[mi] = *(const bf16x8*)&As[(wm + mi * 16 + l15) * SP + ks * 32 + l4 * 8];
#pragma unroll
            for (int ni = 0; ni < 2; ni++)
                bfr[ni] = *(const bf16x8*)&Ws[(wn + ni * 16 + l15) * SP + ks * 32 + l4 * 8];
#pragma unroll
            for (int mi = 0; mi < 2; mi++)
#pragma unroll
                for (int ni = 0; ni < 2; ni++)
                    acc[mi][ni] = __builtin_amdgcn_mfma_f32_16x16x32_bf16(af[mi], bfr[ni], acc[mi][ni], 0, 0, 0);
        }
        __syncthreads();
    }
    if (KS > 1) {
        float* P = C + (size_t)blockIdx.z * M * N;
#pragma unroll
        for (int mi = 0; mi < 2; mi++) {
            int row0 = bm + wm + mi * 16 + l4 * 4;
#pragma unroll
            for (int ni = 0; ni < 2; ni++) {
                int col = bn + wn + ni * 16 + l15;
#pragma unroll
                for (int j = 0; j < 4; j++)
                    P[(size_t)(row0 + j) * N + col] = acc[mi][ni][j];
            }
        }
    } else {
#pragma unroll
        for (int mi = 0; mi < 2; mi++) {
            int row0 = bm + wm + mi * 16 + l4 * 4;
#pragma unroll
            for (int ni = 0; ni < 2; ni++) {
                int col = bn + wn + ni * 16 + l15;
#pragma unroll
                for (int j = 0; j < 4; j++) {
                    int row = row0 + j;
                    float v = acc[mi][ni][j];
                    if (MODE == 1) v = softplusf(v + bias[col]);
                    if (MODE == 2) v = seluf(v + bias[col]);
                    if (MODE == 4) v = softplusf(v + bias[row]);
                    if (C)  C[(size_t)row * N + col] = v;
                    if (Cb) Cb[(size_t)row * N + col] = __float2bfloat16(v);
                }
            }
        }
    }
}

// ---------------- split-K reduce: sum KS partial slices (+ optional bias/resid) ----------------
template<int KS, int RMODE>
__global__ __launch_bounds__(256) void reduce_k(
    const float* __restrict__ P, float* __restrict__ C, bf16* __restrict__ Cb,
    const float* __restrict__ bias, const float* __restrict__ resid,
    int MN, int N)
{
    int i = (blockIdx.x * 256 + threadIdx.x) * 4;
    float4 v = *(const float4*)(P + i);
#pragma unroll
    for (int s = 1; s < KS; s++) {
        float4 u = *(const float4*)(P + (size_t)s * MN + i);
        v.x += u.x; v.y += u.y; v.z += u.z; v.w += u.w;
    }
    if (RMODE == 1) {
        float4 bz = *(const float4*)(bias + (i % N));
        float4 rx = *(const float4*)(resid + i);
        v.x += bz.x + rx.x; v.y += bz.y + rx.y;
        v.z += bz.z + rx.z; v.w += bz.w + rx.w;
    }
    if (C) *(float4*)(C + i) = v;
    if (Cb) {
        bf16* d = Cb + i;
        d[0] = __float2bfloat16(v.x); d[1] = __float2bfloat16(v.y);
        d[2] = __float2bfloat16(v.z); d[3] = __float2bfloat16(v.w);
    }
}

// ---------------- depthwise conv + SiLU, vectorized: 4 channels x 8 positions / thread ----------------
__global__ __launch_bounds__(256) void conv_silu_kernel(
    const float* __restrict__ xz, const float* __restrict__ cw,
    const float* __restrict__ cb, bf16* __restrict__ xcb)
{
    int gid = blockIdx.x * 256 + threadIdx.x;     // 131072 total
    int d4  = (gid & 255) * 4;
    int l0  = ((gid >> 8) & 127) * 8;
    int b   = (gid >> 15) & 1;
    int dir = gid >> 16;
    float wv[4][12];
    {
        const float4* cwp = (const float4*)(cw + d4 * 12);
        float buf[48];
#pragma unroll
        for (int i = 0; i < 12; i++) {
            float4 t = cwp[i];
            buf[4*i] = t.x; buf[4*i+1] = t.y; buf[4*i+2] = t.z; buf[4*i+3] = t.w;
        }
#pragma unroll
        for (int dd = 0; dd < 4; dd++)
#pragma unroll
            for (int k = 0; k < 12; k++) wv[dd][k] = buf[dd * 12 + k];
    }
    float4 cb4 = *(const float4*)(cb + d4);
    float4 tap[19];
    int tbase = (dir == 0) ? (l0 - (K_ - 1)) : l0;
#pragma unroll
    for (int i = 0; i < 19; i++) {
        int ls = tbase + i;
        if (ls >= 0 && ls < L_)
            tap[i] = *(const float4*)(xz + ((size_t)(b * L_ + ls)) * (2 * DI_) + d4);
        else
            tap[i] = make_float4(0.f, 0.f, 0.f, 0.f);
    }
    size_t obase = (size_t)dir * BLD + ((size_t)(b * L_ + l0)) * DI_ + d4;
    if (dir == 0) {
#pragma unroll
        for (int j = 0; j < 8; j++) {
            float a0 = cb4.x, a1 = cb4.y, a2 = cb4.z, a3 = cb4.w;
#pragma unroll
            for (int k = 0; k < K_; k++) {
                float4 t = tap[j + k];
                a0 = fmaf(wv[0][k], t.x, a0); a1 = fmaf(wv[1][k], t.y, a1);
                a2 = fmaf(wv[2][k], t.z, a2); a3 = fmaf(wv[3][k], t.w, a3);
            }
            ushort4 o;
            o.x = bfbits(siluf(a0)); o.y = bfbits(siluf(a1));
            o.z = bfbits(siluf(a2)); o.w = bfbits(siluf(a3));
            *(ushort4*)(xcb + obase + (size_t)j * DI_) = o;
        }
    } else {
#pragma unroll
        for (int j = 0; j < 8; j++) {
            float a0 = cb4.x, a1 = cb4.y, a2 = cb4.z, a3 = cb4.w;
#pragma unroll
            for (int k = 0; k < K_; k++) {
                float4 t = tap[j + (K_ - 1) - k];
                a0 = fmaf(wv[0][k], t.x, a0); a1 = fmaf(wv[1][k], t.y, a1);
                a2 = fmaf(wv[2][k], t.z, a2); a3 = fmaf(wv[3][k], t.w, a3);
            }
            ushort4 o;
            o.x = bfbits(siluf(a0)); o.y = bfbits(siluf(a1));
            o.z = bfbits(siluf(a2)); o.w = bfbits(siluf(a3));
            *(ushort4*)(xcb + obase + (size_t)j * DI_) = o;
        }
    }
}

// ---------------- transpose bf16[2][BL][DI] -> bf16[2][DI][BL] ----------------
__global__ __launch_bounds__(256) void transpose_b_kernel(
    const bf16* __restrict__ in, bf16* __restrict__ out)
{
    __shared__ ushort tile[32][34];
    int dir = blockIdx.z;
    int d0 = blockIdx.x * 32, l0 = blockIdx.y * 32;
    const bf16* ip = in + (size_t)dir * BLD;
    bf16* op = out + (size_t)dir * BLD;
    int tx = threadIdx.x & 31, ty = threadIdx.x >> 5;
#pragma unroll
    for (int r = 0; r < 4; r++) {
        int l = l0 + ty * 4 + r;
        tile[ty * 4 + r][tx] = *(const ushort*)(ip + (size_t)l * DI_ + d0 + tx);
    }
    __syncthreads();
#pragma unroll
    for (int r = 0; r < 4; r++) {
        int d = d0 + ty * 4 + r;
        *(ushort*)(op + (size_t)d * BL + l0 + tx) = tile[tx][ty * 4 + r];
    }
}

// ---------------- chunked selective scan, 4 n-states per lane, transposed inputs ----------------
// block 256 thr = 16 chunks x 4 ngrp x 4 dloc; grid (DI/4, B, 2 dirs)
__global__ __launch_bounds__(256) void scan_kernel(
    const float* __restrict__ dtT,   // [2][DI][BL] f32
    const bf16*  __restrict__ xcT,   // [2][DI][BL] bf16
    const float* __restrict__ dbl,   // [2][BL][64] f32
    const float* __restrict__ A_log, const float* __restrict__ Dp,
    float* __restrict__ y2)          // [2][DI][BL] f32
{
    __shared__ float sA[16][4][17];
    __shared__ float sB[16][4][17];
    __shared__ float sY[4][1028];
    int dgrp = blockIdx.x, b = blockIdx.y, dir = blockIdx.z;
    int tid = threadIdx.x;
    int dloc = tid & 3, ng = (tid >> 2) & 3, c = tid >> 4;
    int d = dgrp * 4 + dloc;
    size_t rowbase = ((size_t)dir * DI_ + d) * BL + (size_t)b * L_;
    const float* dtp = dtT + rowbase;
    const bf16*  xcp = xcT + rowbase;
    const float* dblp = dbl + ((size_t)dir * BL + (size_t)b * L_) * 64;
    int nb = ng * 4;
    float A0 = -__expf(A_log[d * N_ + nb + 0]);
    float A1 = -__expf(A_log[d * N_ + nb + 1]);
    float A2 = -__expf(A_log[d * N_ + nb + 2]);
    float A3 = -__expf(A_log[d * N_ + nb + 3]);
    float Dd = Dp[d];
    int l0 = c * 64;
    // pass 1: local scan -> chunk summaries (per n)
    float ac0=1.f, ac1=1.f, ac2=1.f, ac3=1.f;
    float h0=0.f, h1=0.f, h2=0.f, h3=0.f;
    for (int j = 0; j < 64; j += 4) {
        float4 dt4 = *(const float4*)(dtp + l0 + j);
        ushort4 xcu = *(const ushort4*)(xcp + l0 + j);
#pragma unroll
        for (int q = 0; q < 4; q++) {
            int l = l0 + j + q;
            float dtv = ((const float*)&dt4)[q];
            float xcv = bf2f(((const ushort*)&xcu)[q]);
            float4 B4 = *(const float4*)(dblp + (size_t)l * 64 + DTR_ + nb);
            float dx = dtv * xcv;
            float a0 = __expf(dtv * A0), a1 = __expf(dtv * A1),
                  a2 = __expf(dtv * A2), a3 = __expf(dtv * A3);
            ac0 *= a0; ac1 *= a1; ac2 *= a2; ac3 *= a3;
            h0 = fmaf(a0, h0, dx * B4.x); h1 = fmaf(a1, h1, dx * B4.y);
            h2 = fmaf(a2, h2, dx * B4.z); h3 = fmaf(a3, h3, dx * B4.w);
        }
    }
    sA[c][dloc][nb+0]=ac0; sA[c][dloc][nb+1]=ac1; sA[c][dloc][nb+2]=ac2; sA[c][dloc][nb+3]=ac3;
    sB[c][dloc][nb+0]=h0;  sB[c][dloc][nb+1]=h1;  sB[c][dloc][nb+2]=h2;  sB[c][dloc][nb+3]=h3;
    __syncthreads();
    // exclusive cross-chunk prefix (<=15 steps)
    float p0=0.f, p1=0.f, p2=0.f, p3=0.f;
    for (int cc = 0; cc < c; cc++) {
        p0 = fmaf(sA[cc][dloc][nb+0], p0, sB[cc][dloc][nb+0]);
        p1 = fmaf(sA[cc][dloc][nb+1], p1, sB[cc][dloc][nb+1]);
        p2 = fmaf(sA[cc][dloc][nb+2], p2, sB[cc][dloc][nb+2]);
        p3 = fmaf(sA[cc][dloc][nb+3], p3, sB[cc][dloc][nb+3]);
    }
    h0 = p0; h1 = p1; h2 = p2; h3 = p3;
    // pass 2: rescan + reduce over n (in-reg 4 + 2 shfl over ngrp)
    for (int j = 0; j < 64; j += 4) {
        float4 dt4 = *(const float4*)(dtp + l0 + j);
        ushort4 xcu = *(const ushort4*)(xcp + l0 + j);
#pragma unroll
        for (int q = 0; q < 4; q++) {
            int l = l0 + j + q;
            float dtv = ((const float*)&dt4)[q];
            float xcv = bf2f(((const ushort*)&xcu)[q]);
            float4 B4 = *(const float4*)(dblp + (size_t)l * 64 + DTR_ + nb);
            float4 C4 = *(const float4*)(dblp + (size_t)l * 64 + DTR_ + N_ + nb);
            float dx = dtv * xcv;
            float a0 = __expf(dtv * A0), a1 = __expf(dtv * A1),
                  a2 = __expf(dtv * A2), a3 = __expf(dtv * A3);
            h0 = fmaf(a0, h0, dx * B4.x); h1 = fmaf(a1, h1, dx * B4.y);
            h2 = fmaf(a2, h2, dx * B4.z); h3 = fmaf(a3, h3, dx * B4.w);
            float p = h0 * C4.x;
            p = fmaf(h1, C4.y, p); p = fmaf(h2, C4.z, p); p = fmaf(h3, C4.w, p);
            p += __shfl_xor(p, 4); p += __shfl_xor(p, 8);
            if (ng == 0) sY[dloc][l] = fmaf(xcv, Dd, p);
        }
    }
    __syncthreads();
    // coalesced write: 4 d-rows x 1024 l
    float* yp = y2 + ((size_t)dir * DI_ + (size_t)dgrp * 4) * BL + (size_t)b * L_;
    int lw = tid * 4;
#pragma unroll
    for (int dd = 0; dd < 4; dd++)
        *(float4*)(yp + (size_t)dd * BL + lw) = *(float4*)&sY[dd][lw];
}

// ---------------- combine + transpose: ycomb_b[bl][d] = (y2_f+y2_b)[d][bl] * silu(z) ----------------
__global__ __launch_bounds__(256) void combine_kernel(
    const float* __restrict__ y2, const float* __restrict__ xz,
    bf16* __restrict__ yc)
{
    __shared__ float tile[32][33];
    int d0 = blockIdx.x * 32, bl0 = blockIdx.y * 32;
    int tx = threadIdx.x & 31, ty = threadIdx.x >> 5;
#pragma unroll
    for (int r = 0; r < 4; r++) {
        int d = d0 + ty * 4 + r;
        tile[ty * 4 + r][tx] = y2[(size_t)d * BL + bl0 + tx]
                             + y2[(size_t)(DI_ + d) * BL + bl0 + tx];
    }
    __syncthreads();
#pragma unroll
    for (int r = 0; r < 4; r++) {
        int bl = bl0 + ty * 4 + r;
        float z = xz[(size_t)bl * (2 * DI_) + DI_ + d0 + tx];
        yc[(size_t)bl * DI_ + d0 + tx] = __float2bfloat16(tile[tx][ty * 4 + r] * siluf(z));
    }
}

extern "C" void kernel_launch(void* const* d_in, const int* in_sizes, int n_in,
                              void* d_out, int out_size, void* d_ws, size_t ws_size,
                              hipStream_t stream) {
    const float* x     = (const float*)d_in[0];
    const float* mask  = (const float*)d_in[1];
    const float* n1w   = (const float*)d_in[2];
    const float* n1b   = (const float*)d_in[3];
    const float* n2w   = (const float*)d_in[4];
    const float* n2b   = (const float*)d_in[5];
    const float* ff1w  = (const float*)d_in[6];
    const float* ff1b  = (const float*)d_in[7];
    const float* ff2w  = (const float*)d_in[8];
    const float* ff2b  = (const float*)d_in[9];
    const float* inpw  = (const float*)d_in[10];
    const float* convw = (const float*)d_in[11];
    const float* convb = (const float*)d_in[12];
    const float* xpw   = (const float*)d_in[13];
    const float* dtpw  = (const float*)d_in[14];
    const float *A_log, *Dp, *outpw, *dtpb;
    if (in_sizes[15] == DI_ * N_) {
        A_log = (const float*)d_in[15]; Dp = (const float*)d_in[16];
        outpw = (const float*)d_in[17]; dtpb = (const float*)d_in[18];
    } else {
        dtpb = (const float*)d_in[15]; A_log = (const float*)d_in[16];
        Dp = (const float*)d_in[17]; outpw = (const float*)d_in[18];
    }

    float* ws = (float*)d_ws;
    bf16*  wb      = (bf16*)ws;                         // 1884160 fu
    float* xz      = ws + 1884160;                      // 4194304 fu (also P9/P12)
    bf16*  xn_b    = (bf16*)(ws + 6078464);             // 524288 fu (also mon_b)
    bf16*  xc_b    = (bf16*)(ws + 6602752);             // 2097152 fu (also h_b)
    float* y2      = ws + 8699904;                      // 4194304 fu  [2][DI][BL]
    float* dblb    = ws + 12894208;                     // 262144 fu
    bf16*  dbl_b   = (bf16*)(ws + 13156352);            // 131072 fu
    float* dtT     = ws + 13287424;                     // 4194304 fu (also P5, moraw)
    bf16*  xcT_b   = (bf16*)(ws + 17481728);            // 2097152 fu [2][DI][BL] bf16
    bf16*  ycomb_b = (bf16*)(ws + 19578880);            // 524288 fu

    bf16* inpw_b = wb;
    bf16* xpw_b  = wb + 1048576;
    bf16* dtpw_b = wb + 1114112;
    bf16* outpw_b= wb + 1146880;
    bf16* ff1w_b = wb + 1671168;
    bf16* ff2w_b = wb + 2719744;
    bf16* mon_b  = xn_b;
    bf16* h_b    = xc_b;
    float* moraw = dtT;
    float* P5    = dtT;
    float* P9    = xz;
    float* P12   = xz;

    // 0. cast weights to bf16
    cast_w<<<dim3(3680), 256, 0, stream>>>(inpw, xpw, dtpw, outpw, ff1w, ff2w, wb);
    // 1. xn = LN(x) -> bf16
    ln_kernel<<<dim3(BL / 4), 256, 0, stream>>>(x, n1w, n1b, nullptr, xn_b);
    // 2. xz = xn @ in_proj_w^T (2048x2048x512), grid 1024
    mgemm_k<0, 64, 1><<<dim3(32, 32), 256, 0, stream>>>(
        (const short*)xn_b, DM_, (const short*)inpw_b, DM_, xz, nullptr,
        nullptr, BL, 2 * DI_, DM_);
    // 3. conv + silu -> bf16 (vectorized 4ch x 8pos)
    conv_silu_kernel<<<dim3(512), 256, 0, stream>>>(xz, convw, convb, xc_b);
    // 4. xcT_b = bf16 transpose(xc_b)
    transpose_b_kernel<<<dim3(DI_ / 32, BL / 32, 2), 256, 0, stream>>>(xc_b, xcT_b);
    // 5. dbl = xc @ x_proj_w^T (4096x64x1024), split-K 8, grid 512
    mgemm_k<0, 64, 8><<<dim3(1, 64, 8), 256, 0, stream>>>(
        (const short*)xc_b, DI_, (const short*)xpw_b, DI_, P5, nullptr,
        nullptr, 2 * BL, 64, DI_);
    reduce_k<8, 0><<<dim3(256), 256, 0, stream>>>(P5, dblb, dbl_b, nullptr, nullptr,
                                                  2 * BL * 64, 64);
    // 6. dtT = softplus(dt_proj_w @ dt_r^T + b[m]) -> f32 [DI][BL] per dir, grid 512 each
    for (int dir = 0; dir < 2; dir++)
        mgemm_k<4, 32, 1><<<dim3(32, 16), 256, 0, stream>>>(
            (const short*)dtpw_b, DTR_, (const short*)(dbl_b + (size_t)dir * BL * 64), 64,
            dtT + (size_t)dir * (size_t)DI_ * BL, nullptr, dtpb, DI_, BL, DTR_);
    // 7. chunked scan (both dirs, one launch) -> y2[2][DI][BL]
    scan_kernel<<<dim3(DI_ / 4, B_, 2), 256, 0, stream>>>(dtT, xcT_b, dblb, A_log, Dp, y2);
    // 8. ycomb_b = (y2_f + y2_b)^T * silu(z) -> bf16
    combine_kernel<<<dim3(DI_ / 32, BL / 32), 256, 0, stream>>>(y2, xz, ycomb_b);
    // 9. mo_raw = ycomb @ out_proj_w^T (2048x512x1024), split-K 2, grid 512
    mgemm_k<0, 64, 2><<<dim3(8, 32, 2), 256, 0, stream>>>(
        (const short*)ycomb_b, DI_, (const short*)outpw_b, DI_, P9, nullptr,
        nullptr, BL, DM_, DI_);
    reduce_k<2, 0><<<dim3(1024), 256, 0, stream>>>(P9, moraw, nullptr, nullptr, nullptr,
                                                   BL * DM_, DM_);
    // 10. mo_n = LN(mo_raw * mask) -> bf16
    ln_kernel<<<dim3(BL / 4), 256, 0, stream>>>(moraw, n2w, n2b, mask, mon_b);
    // 11. h = selu(mo_n @ ff1_w^T + b) -> bf16 (2048x2048x512), grid 1024
    mgemm_k<2, 64, 1><<<dim3(32, 32), 256, 0, stream>>>(
        (const short*)mon_b, DM_, (const short*)ff1w_b, DM_, nullptr, h_b,
        ff1b, BL, 4 * DM_, DM_);
    // 12. out = h @ ff2_w^T (2048x512x2048), split-K 2, grid 512; reduce adds bias + x
    mgemm_k<0, 64, 2><<<dim3(8, 32, 2), 256, 0, stream>>>(
        (const short*)h_b, 4 * DM_, (const short*)ff2w_b, 4 * DM_, P12, nullptr,
        nullptr, BL, DM_, 4 * DM_);
    reduce_k<2, 1><<<dim3(1024), 256, 0, stream>>>(P12, (float*)d_out, nullptr, ff2b, x,
                                                   BL * DM_, DM_);
}

// Round 9
// 193.999 us; speedup vs baseline: 4.7467x; 1.0682x over previous
//
#include <hip/hip_runtime.h>
#include <hip/hip_bf16.h>

typedef __hip_bfloat16 bf16;

#define B_   2
#define L_   1024
#define DM_  512
#define DI_  1024
#define N_   16
#define K_   12
#define DTR_ 32

static constexpr int BLD  = B_ * L_ * DI_;   // 2097152
static constexpr int BL   = B_ * L_;         // 2048

using bf16x8 = __attribute__((ext_vector_type(8))) short;
using f32x4  = __attribute__((ext_vector_type(4))) float;
using u16x8  = __attribute__((ext_vector_type(8))) unsigned short;

__device__ __forceinline__ float siluf(float x) { return x / (1.f + __expf(-x)); }
__device__ __forceinline__ float softplusf(float x) {
    return fmaxf(x, 0.f) + log1pf(expf(-fabsf(x)));
}
__device__ __forceinline__ float seluf(float x) {
    const float lam = 1.0507009873554805f, alp = 1.6732632423543772f;
    return x > 0.f ? lam * x : lam * alp * (expf(x) - 1.f);
}
__device__ __forceinline__ ushort bfbits(float x) {
    bf16 v = __float2bfloat16(x);
    return *(ushort*)&v;
}
__device__ __forceinline__ float bf2f(ushort u) {
    return __uint_as_float(((unsigned)u) << 16);
}

// ---------------- weight cast f32 -> bf16 (6 segments, vec4) ----------------
__global__ __launch_bounds__(256) void cast_w(
    const float* __restrict__ s0, const float* __restrict__ s1, const float* __restrict__ s2,
    const float* __restrict__ s3, const float* __restrict__ s4, const float* __restrict__ s5,
    bf16* __restrict__ dst)
{
    int i = blockIdx.x * 256 + threadIdx.x;   // total 942080 vec4
    const float* src; int off;
    if (i < 262144)      { src = s0; off = i; }
    else if (i < 278528) { src = s1; off = i - 262144; }
    else if (i < 286720) { src = s2; off = i - 278528; }
    else if (i < 417792) { src = s3; off = i - 286720; }
    else if (i < 679936) { src = s4; off = i - 417792; }
    else                 { src = s5; off = i - 679936; }
    float4 v = ((const float4*)src)[off];
    bf16* d = dst + (size_t)i * 4;
    d[0] = __float2bfloat16(v.x); d[1] = __float2bfloat16(v.y);
    d[2] = __float2bfloat16(v.z); d[3] = __float2bfloat16(v.w);
}

// ---------------- LayerNorm: one wave per row of 512, bf16 out ----------------
__global__ __launch_bounds__(256) void ln_kernel(
    const float* __restrict__ x, const float* __restrict__ w, const float* __restrict__ b,
    const float* __restrict__ mask, bf16* __restrict__ y)
{
    int row  = blockIdx.x * 4 + (threadIdx.x >> 6);
    int lane = threadIdx.x & 63;
    const float* xr = x + (size_t)row * DM_;
    float mval = mask ? mask[row] : 1.0f;
    float v[8];
    float s = 0.f, ss = 0.f;
#pragma unroll
    for (int i = 0; i < 8; i++) {
        v[i] = xr[lane + i * 64] * mval;
        s += v[i]; ss += v[i] * v[i];
    }
#pragma unroll
    for (int o = 32; o >= 1; o >>= 1) { s += __shfl_xor(s, o); ss += __shfl_xor(ss, o); }
    float mean = s * (1.f / DM_);
    float var  = ss * (1.f / DM_) - mean * mean;
    float r    = rsqrtf(var + 1e-5f);
    bf16* yr = y + (size_t)row * DM_;
#pragma unroll
    for (int i = 0; i < 8; i++) {
        int c = lane + i * 64;
        yr[c] = __float2bfloat16((v[i] - mean) * r * w[c] + b[c]);
    }
}

// ---------------- MFMA GEMM: C(M,N) = A(M,K) @ W(N,K)^T  (bf16 in, fp32 acc) ----------------
// KS>1: write fp32 partials. KS==1 MODE: 0 plain  1 bias[n]+softplus  2 bias[n]+selu  4 bias[m]+softplus
template<int MODE, int BK, int KS>
__global__ __launch_bounds__(256) void mgemm_k(
    const short* __restrict__ A, int lda,
    const short* __restrict__ W, int ldw,
    float* __restrict__ C, bf16* __restrict__ Cb,
    const float* __restrict__ bias,
    int M, int N, int Kd)
{
    constexpr int SP = BK + 8;                // padded LDS row stride (bf16 elems)
    __shared__ short As[64 * SP];
    __shared__ short Ws[64 * SP];
    int bm = blockIdx.y * 64, bn = blockIdx.x * 64;
    int tid = threadIdx.x;
    int lane = tid & 63, w = tid >> 6;
    int wm = (w >> 1) * 32, wn = (w & 1) * 32;
    int l15 = lane & 15, l4 = lane >> 4;
    f32x4 acc[2][2] = {};
    int srow = tid >> 2;
    int scol = (tid & 3) * (BK / 4);
    int kbeg = (KS > 1) ? blockIdx.z * (Kd / KS) : 0;
    int kend = (KS > 1) ? kbeg + Kd / KS : Kd;
    const short* Ap = A + (size_t)(bm + srow) * lda + scol;
    const short* Wp = W + (size_t)(bn + srow) * ldw + scol;
    short* Asw = &As[srow * SP + scol];
    short* Wsw = &Ws[srow * SP + scol];
    for (int k0 = kbeg; k0 < kend; k0 += BK) {
#pragma unroll
        for (int i = 0; i < BK / 32; i++) {
            *(bf16x8*)(Asw + i * 8) = *(const bf16x8*)(Ap + k0 + i * 8);
            *(bf16x8*)(Wsw + i * 8) = *(const bf16x8*)(Wp + k0 + i * 8);
        }
        __syncthreads();
#pragma unroll
        for (int ks = 0; ks < BK / 32; ks++) {
            bf16x8 af[2], bfr[2];
#pragma unroll
            for (int mi = 0; mi < 2; mi++)
                af[mi] = *(const bf16x8*)&As[(wm + mi * 16 + l15) * SP + ks * 32 + l4 * 8];
#pragma unroll
            for (int ni = 0; ni < 2; ni++)
                bfr[ni] = *(const bf16x8*)&Ws[(wn + ni * 16 + l15) * SP + ks * 32 + l4 * 8];
#pragma unroll
            for (int mi = 0; mi < 2; mi++)
#pragma unroll
                for (int ni = 0; ni < 2; ni++)
                    acc[mi][ni] = __builtin_amdgcn_mfma_f32_16x16x32_bf16(af[mi], bfr[ni], acc[mi][ni], 0, 0, 0);
        }
        __syncthreads();
    }
    if (KS > 1) {
        float* P = C + (size_t)blockIdx.z * M * N;
#pragma unroll
        for (int mi = 0; mi < 2; mi++) {
            int row0 = bm + wm + mi * 16 + l4 * 4;
#pragma unroll
            for (int ni = 0; ni < 2; ni++) {
                int col = bn + wn + ni * 16 + l15;
#pragma unroll
                for (int j = 0; j < 4; j++)
                    P[(size_t)(row0 + j) * N + col] = acc[mi][ni][j];
            }
        }
    } else {
#pragma unroll
        for (int mi = 0; mi < 2; mi++) {
            int row0 = bm + wm + mi * 16 + l4 * 4;
#pragma unroll
            for (int ni = 0; ni < 2; ni++) {
                int col = bn + wn + ni * 16 + l15;
#pragma unroll
                for (int j = 0; j < 4; j++) {
                    int row = row0 + j;
                    float v = acc[mi][ni][j];
                    if (MODE == 1) v = softplusf(v + bias[col]);
                    if (MODE == 2) v = seluf(v + bias[col]);
                    if (MODE == 4) v = softplusf(v + bias[row]);
                    if (C)  C[(size_t)row * N + col] = v;
                    if (Cb) Cb[(size_t)row * N + col] = __float2bfloat16(v);
                }
            }
        }
    }
}

// ---------------- split-K reduce: sum KS partial slices (+ optional bias/resid) ----------------
template<int KS, int RMODE>
__global__ __launch_bounds__(256) void reduce_k(
    const float* __restrict__ P, float* __restrict__ C, bf16* __restrict__ Cb,
    const float* __restrict__ bias, const float* __restrict__ resid,
    int MN, int N)
{
    int i = (blockIdx.x * 256 + threadIdx.x) * 4;
    float4 v = *(const float4*)(P + i);
#pragma unroll
    for (int s = 1; s < KS; s++) {
        float4 u = *(const float4*)(P + (size_t)s * MN + i);
        v.x += u.x; v.y += u.y; v.z += u.z; v.w += u.w;
    }
    if (RMODE == 1) {
        float4 bz = *(const float4*)(bias + (i % N));
        float4 rx = *(const float4*)(resid + i);
        v.x += bz.x + rx.x; v.y += bz.y + rx.y;
        v.z += bz.z + rx.z; v.w += bz.w + rx.w;
    }
    if (C) *(float4*)(C + i) = v;
    if (Cb) {
        bf16* d = Cb + i;
        d[0] = __float2bfloat16(v.x); d[1] = __float2bfloat16(v.y);
        d[2] = __float2bfloat16(v.z); d[3] = __float2bfloat16(v.w);
    }
}

// ---------------- depthwise conv + SiLU: 4 ch x 8 pos / thread, dual output (row + transposed) ----------------
__global__ __launch_bounds__(256) void conv_silu_kernel(
    const float* __restrict__ xz, const float* __restrict__ cw,
    const float* __restrict__ cb, bf16* __restrict__ xcb, bf16* __restrict__ xcbT)
{
    int gid = blockIdx.x * 256 + threadIdx.x;     // 131072 total
    int d4  = (gid & 255) * 4;
    int l0  = ((gid >> 8) & 127) * 8;
    int b   = (gid >> 15) & 1;
    int dir = gid >> 16;
    float wv[4][12];
    {
        const float4* cwp = (const float4*)(cw + d4 * 12);
        float buf[48];
#pragma unroll
        for (int i = 0; i < 12; i++) {
            float4 t = cwp[i];
            buf[4*i] = t.x; buf[4*i+1] = t.y; buf[4*i+2] = t.z; buf[4*i+3] = t.w;
        }
#pragma unroll
        for (int dd = 0; dd < 4; dd++)
#pragma unroll
            for (int k = 0; k < 12; k++) wv[dd][k] = buf[dd * 12 + k];
    }
    float4 cb4 = *(const float4*)(cb + d4);
    float4 tap[19];
    int tbase = (dir == 0) ? (l0 - (K_ - 1)) : l0;
#pragma unroll
    for (int i = 0; i < 19; i++) {
        int ls = tbase + i;
        if (ls >= 0 && ls < L_)
            tap[i] = *(const float4*)(xz + ((size_t)(b * L_ + ls)) * (2 * DI_) + d4);
        else
            tap[i] = make_float4(0.f, 0.f, 0.f, 0.f);
    }
    ushort ot[4][8];
#pragma unroll
    for (int j = 0; j < 8; j++) {
        float a0 = cb4.x, a1 = cb4.y, a2 = cb4.z, a3 = cb4.w;
        if (dir == 0) {
#pragma unroll
            for (int k = 0; k < K_; k++) {
                float4 t = tap[j + k];
                a0 = fmaf(wv[0][k], t.x, a0); a1 = fmaf(wv[1][k], t.y, a1);
                a2 = fmaf(wv[2][k], t.z, a2); a3 = fmaf(wv[3][k], t.w, a3);
            }
        } else {
#pragma unroll
            for (int k = 0; k < K_; k++) {
                float4 t = tap[j + (K_ - 1) - k];
                a0 = fmaf(wv[0][k], t.x, a0); a1 = fmaf(wv[1][k], t.y, a1);
                a2 = fmaf(wv[2][k], t.z, a2); a3 = fmaf(wv[3][k], t.w, a3);
            }
        }
        ot[0][j] = bfbits(siluf(a0)); ot[1][j] = bfbits(siluf(a1));
        ot[2][j] = bfbits(siluf(a2)); ot[3][j] = bfbits(siluf(a3));
    }
    // row-major store [bl][d]
    size_t obase = (size_t)dir * BLD + ((size_t)(b * L_ + l0)) * DI_ + d4;
#pragma unroll
    for (int j = 0; j < 8; j++) {
        ushort4 o; o.x = ot[0][j]; o.y = ot[1][j]; o.z = ot[2][j]; o.w = ot[3][j];
        *(ushort4*)(xcb + obase + (size_t)j * DI_) = o;
    }
    // transposed store [d][bl]
#pragma unroll
    for (int dd = 0; dd < 4; dd++) {
        u16x8 v;
#pragma unroll
        for (int j = 0; j < 8; j++) v[j] = ot[dd][j];
        *(u16x8*)(xcbT + ((size_t)dir * DI_ + d4 + dd) * BL + (size_t)b * L_ + l0) = v;
    }
}

// ---------------- chunked selective scan: 32 chunks x 32 steps, 4 n / lane ----------------
// block 256 thr = 32 chunks x 4 ngrp x 2 dloc; grid (DI/2, B, 2 dirs) = 2048 blocks
__global__ __launch_bounds__(256, 8) void scan_kernel(
    const float* __restrict__ dtT,   // [2][DI][BL] f32
    const bf16*  __restrict__ xcT,   // [2][DI][BL] bf16
    const float* __restrict__ dbl,   // [2][BL][64] f32
    const float* __restrict__ A_log, const float* __restrict__ Dp,
    float* __restrict__ y2)          // [2][DI][BL] f32
{
    __shared__ float sA[32][2][17];
    __shared__ float sB[32][2][17];
    __shared__ float sY[2][32][36];
    int dgrp = blockIdx.x, b = blockIdx.y, dir = blockIdx.z;
    int tid = threadIdx.x;
    int dloc = tid & 1, ng = (tid >> 1) & 3, c = tid >> 3;
    int d = dgrp * 2 + dloc;
    size_t rowbase = ((size_t)dir * DI_ + d) * BL + (size_t)b * L_;
    const float* dtp = dtT + rowbase;
    const bf16*  xcp = xcT + rowbase;
    const float* dblp = dbl + ((size_t)dir * BL + (size_t)b * L_) * 64;
    int nb = ng * 4;
    float A0 = -__expf(A_log[d * N_ + nb + 0]);
    float A1 = -__expf(A_log[d * N_ + nb + 1]);
    float A2 = -__expf(A_log[d * N_ + nb + 2]);
    float A3 = -__expf(A_log[d * N_ + nb + 3]);
    float Dd = Dp[d];
    int l0 = c * 32;
    // pass 1: local scan -> chunk summaries
    float ac0=1.f, ac1=1.f, ac2=1.f, ac3=1.f;
    float h0=0.f, h1=0.f, h2=0.f, h3=0.f;
    for (int j = 0; j < 32; j += 4) {
        float4 dt4 = *(const float4*)(dtp + l0 + j);
        ushort4 xcu = *(const ushort4*)(xcp + l0 + j);
#pragma unroll
        for (int q = 0; q < 4; q++) {
            int l = l0 + j + q;
            float dtv = ((const float*)&dt4)[q];
            float xcv = bf2f(((const ushort*)&xcu)[q]);
            float4 B4 = *(const float4*)(dblp + (size_t)l * 64 + DTR_ + nb);
            float dx = dtv * xcv;
            float a0 = __expf(dtv * A0), a1 = __expf(dtv * A1),
                  a2 = __expf(dtv * A2), a3 = __expf(dtv * A3);
            ac0 *= a0; ac1 *= a1; ac2 *= a2; ac3 *= a3;
            h0 = fmaf(a0, h0, dx * B4.x); h1 = fmaf(a1, h1, dx * B4.y);
            h2 = fmaf(a2, h2, dx * B4.z); h3 = fmaf(a3, h3, dx * B4.w);
        }
    }
    sA[c][dloc][nb+0]=ac0; sA[c][dloc][nb+1]=ac1; sA[c][dloc][nb+2]=ac2; sA[c][dloc][nb+3]=ac3;
    sB[c][dloc][nb+0]=h0;  sB[c][dloc][nb+1]=h1;  sB[c][dloc][nb+2]=h2;  sB[c][dloc][nb+3]=h3;
    __syncthreads();
    // exclusive cross-chunk prefix (<=31 steps)
    float p0=0.f, p1=0.f, p2=0.f, p3=0.f;
    for (int cc = 0; cc < c; cc++) {
        p0 = fmaf(sA[cc][dloc][nb+0], p0, sB[cc][dloc][nb+0]);
        p1 = fmaf(sA[cc][dloc][nb+1], p1, sB[cc][dloc][nb+1]);
        p2 = fmaf(sA[cc][dloc][nb+2], p2, sB[cc][dloc][nb+2]);
        p3 = fmaf(sA[cc][dloc][nb+3], p3, sB[cc][dloc][nb+3]);
    }
    h0 = p0; h1 = p1; h2 = p2; h3 = p3;
    // pass 2: rescan + n-reduce (in-reg 4 + shfl over ng bits 1..2)
    for (int j = 0; j < 32; j += 4) {
        float4 dt4 = *(const float4*)(dtp + l0 + j);
        ushort4 xcu = *(const ushort4*)(xcp + l0 + j);
#pragma unroll
        for (int q = 0; q < 4; q++) {
            int l = l0 + j + q;
            float dtv = ((const float*)&dt4)[q];
            float xcv = bf2f(((const ushort*)&xcu)[q]);
            float4 B4 = *(const float4*)(dblp + (size_t)l * 64 + DTR_ + nb);
            float4 C4 = *(const float4*)(dblp + (size_t)l * 64 + DTR_ + N_ + nb);
            float dx = dtv * xcv;
            float a0 = __expf(dtv * A0), a1 = __expf(dtv * A1),
                  a2 = __expf(dtv * A2), a3 = __expf(dtv * A3);
            h0 = fmaf(a0, h0, dx * B4.x); h1 = fmaf(a1, h1, dx * B4.y);
            h2 = fmaf(a2, h2, dx * B4.z); h3 = fmaf(a3, h3, dx * B4.w);
            float p = h0 * C4.x;
            p = fmaf(h1, C4.y, p); p = fmaf(h2, C4.z, p); p = fmaf(h3, C4.w, p);
            p += __shfl_xor(p, 2); p += __shfl_xor(p, 4);
            if (ng == 0) sY[dloc][c][j + q] = fmaf(xcv, Dd, p);
        }
    }
    __syncthreads();
    // coalesced write: 2 d-rows x 1024 l
    float* yp = y2 + ((size_t)dir * DI_ + (size_t)dgrp * 2) * BL + (size_t)b * L_;
    int lw = tid * 4;
    int cw = tid >> 3, jw = lw & 31;
#pragma unroll
    for (int dd = 0; dd < 2; dd++)
        *(float4*)(yp + (size_t)dd * BL + lw) = *(float4*)&sY[dd][cw][jw];
}

// ---------------- combine + transpose: ycomb_b[bl][d] = (y2_f+y2_b)[d][bl] * silu(z) ----------------
__global__ __launch_bounds__(256) void combine_kernel(
    const float* __restrict__ y2, const float* __restrict__ xz,
    bf16* __restrict__ yc)
{
    __shared__ float tile[32][33];
    int d0 = blockIdx.x * 32, bl0 = blockIdx.y * 32;
    int tx = threadIdx.x & 31, ty = threadIdx.x >> 5;
#pragma unroll
    for (int r = 0; r < 4; r++) {
        int d = d0 + ty * 4 + r;
        tile[ty * 4 + r][tx] = y2[(size_t)d * BL + bl0 + tx]
                             + y2[(size_t)(DI_ + d) * BL + bl0 + tx];
    }
    __syncthreads();
#pragma unroll
    for (int r = 0; r < 4; r++) {
        int bl = bl0 + ty * 4 + r;
        float z = xz[(size_t)bl * (2 * DI_) + DI_ + d0 + tx];
        yc[(size_t)bl * DI_ + d0 + tx] = __float2bfloat16(tile[tx][ty * 4 + r] * siluf(z));
    }
}

extern "C" void kernel_launch(void* const* d_in, const int* in_sizes, int n_in,
                              void* d_out, int out_size, void* d_ws, size_t ws_size,
                              hipStream_t stream) {
    const float* x     = (const float*)d_in[0];
    const float* mask  = (const float*)d_in[1];
    const float* n1w   = (const float*)d_in[2];
    const float* n1b   = (const float*)d_in[3];
    const float* n2w   = (const float*)d_in[4];
    const float* n2b   = (const float*)d_in[5];
    const float* ff1w  = (const float*)d_in[6];
    const float* ff1b  = (const float*)d_in[7];
    const float* ff2w  = (const float*)d_in[8];
    const float* ff2b  = (const float*)d_in[9];
    const float* inpw  = (const float*)d_in[10];
    const float* convw = (const float*)d_in[11];
    const float* convb = (const float*)d_in[12];
    const float* xpw   = (const float*)d_in[13];
    const float* dtpw  = (const float*)d_in[14];
    const float *A_log, *Dp, *outpw, *dtpb;
    if (in_sizes[15] == DI_ * N_) {
        A_log = (const float*)d_in[15]; Dp = (const float*)d_in[16];
        outpw = (const float*)d_in[17]; dtpb = (const float*)d_in[18];
    } else {
        dtpb = (const float*)d_in[15]; A_log = (const float*)d_in[16];
        Dp = (const float*)d_in[17]; outpw = (const float*)d_in[18];
    }

    float* ws = (float*)d_ws;
    bf16*  wb      = (bf16*)ws;                         // 1884160 fu
    float* xz      = ws + 1884160;                      // 4194304 fu (also P9/P12)
    bf16*  xn_b    = (bf16*)(ws + 6078464);             // 524288 fu (also mon_b)
    bf16*  xc_b    = (bf16*)(ws + 6602752);             // 2097152 fu (also h_b)
    float* y2      = ws + 8699904;                      // 4194304 fu  [2][DI][BL]
    float* dblb    = ws + 12894208;                     // 262144 fu
    bf16*  dbl_b   = (bf16*)(ws + 13156352);            // 131072 fu
    float* dtT     = ws + 13287424;                     // 4194304 fu (also P5, moraw)
    bf16*  xcT_b   = (bf16*)(ws + 17481728);            // 2097152 fu [2][DI][BL] bf16
    bf16*  ycomb_b = (bf16*)(ws + 19578880);            // 524288 fu

    bf16* inpw_b = wb;
    bf16* xpw_b  = wb + 1048576;
    bf16* dtpw_b = wb + 1114112;
    bf16* outpw_b= wb + 1146880;
    bf16* ff1w_b = wb + 1671168;
    bf16* ff2w_b = wb + 2719744;
    bf16* mon_b  = xn_b;
    bf16* h_b    = xc_b;
    float* moraw = dtT;
    float* P5    = dtT;
    float* P9    = xz;
    float* P12   = xz;

    // 0. cast weights to bf16
    cast_w<<<dim3(3680), 256, 0, stream>>>(inpw, xpw, dtpw, outpw, ff1w, ff2w, wb);
    // 1. xn = LN(x) -> bf16
    ln_kernel<<<dim3(BL / 4), 256, 0, stream>>>(x, n1w, n1b, nullptr, xn_b);
    // 2. xz = xn @ in_proj_w^T (2048x2048x512), grid 1024
    mgemm_k<0, 64, 1><<<dim3(32, 32), 256, 0, stream>>>(
        (const short*)xn_b, DM_, (const short*)inpw_b, DM_, xz, nullptr,
        nullptr, BL, 2 * DI_, DM_);
    // 3. conv + silu -> xc_b [bl][d] AND xcT_b [d][bl]
    conv_silu_kernel<<<dim3(512), 256, 0, stream>>>(xz, convw, convb, xc_b, xcT_b);
    // 4. dbl = xc @ x_proj_w^T (4096x64x1024), split-K 8, grid 512
    mgemm_k<0, 64, 8><<<dim3(1, 64, 8), 256, 0, stream>>>(
        (const short*)xc_b, DI_, (const short*)xpw_b, DI_, P5, nullptr,
        nullptr, 2 * BL, 64, DI_);
    reduce_k<8, 0><<<dim3(256), 256, 0, stream>>>(P5, dblb, dbl_b, nullptr, nullptr,
                                                  2 * BL * 64, 64);
    // 5. dtT = softplus(dt_proj_w @ dt_r^T + b[m]) -> f32 [DI][BL] per dir, grid 512 each
    for (int dir = 0; dir < 2; dir++)
        mgemm_k<4, 32, 1><<<dim3(32, 16), 256, 0, stream>>>(
            (const short*)dtpw_b, DTR_, (const short*)(dbl_b + (size_t)dir * BL * 64), 64,
            dtT + (size_t)dir * (size_t)DI_ * BL, nullptr, dtpb, DI_, BL, DTR_);
    // 6. chunked scan (both dirs, one launch, 2048 blocks) -> y2[2][DI][BL]
    scan_kernel<<<dim3(DI_ / 2, B_, 2), 256, 0, stream>>>(dtT, xcT_b, dblb, A_log, Dp, y2);
    // 7. ycomb_b = (y2_f + y2_b)^T * silu(z) -> bf16
    combine_kernel<<<dim3(DI_ / 32, BL / 32), 256, 0, stream>>>(y2, xz, ycomb_b);
    // 8. mo_raw = ycomb @ out_proj_w^T (2048x512x1024), split-K 2, grid 512
    mgemm_k<0, 64, 2><<<dim3(8, 32, 2), 256, 0, stream>>>(
        (const short*)ycomb_b, DI_, (const short*)outpw_b, DI_, P9, nullptr,
        nullptr, BL, DM_, DI_);
    reduce_k<2, 0><<<dim3(1024), 256, 0, stream>>>(P9, moraw, nullptr, nullptr, nullptr,
                                                   BL * DM_, DM_);
    // 9. mo_n = LN(mo_raw * mask) -> bf16
    ln_kernel<<<dim3(BL / 4), 256, 0, stream>>>(moraw, n2w, n2b, mask, mon_b);
    // 10. h = selu(mo_n @ ff1_w^T + b) -> bf16 (2048x2048x512), grid 1024
    mgemm_k<2, 64, 1><<<dim3(32, 32), 256, 0, stream>>>(
        (const short*)mon_b, DM_, (const short*)ff1w_b, DM_, nullptr, h_b,
        ff1b, BL, 4 * DM_, DM_);
    // 11. out = h @ ff2_w^T (2048x512x2048), split-K 2, grid 512; reduce adds bias + x
    mgemm_k<0, 64, 2><<<dim3(8, 32, 2), 256, 0, stream>>>(
        (const short*)h_b, 4 * DM_, (const short*)ff2w_b, 4 * DM_, P12, nullptr,
        nullptr, BL, DM_, 4 * DM_);
    reduce_k<2, 1><<<dim3(1024), 256, 0, stream>>>(P12, (float*)d_out, nullptr, ff2b, x,
                                                   BL * DM_, DM_);
}